// Round 6
// baseline (286.259 us; speedup 1.0000x reference)
//
#include <hip/hip_runtime.h>

typedef _Float16 half_t;
typedef _Float16 f16x8 __attribute__((ext_vector_type(8)));
typedef _Float16 f16x4 __attribute__((ext_vector_type(4)));
typedef _Float16 f16x2 __attribute__((ext_vector_type(2)));
typedef float f32x4 __attribute__((ext_vector_type(4)));
typedef float f32x2 __attribute__((ext_vector_type(2)));
typedef float f32x16 __attribute__((ext_vector_type(16)));

#define D_MODEL 1024
#define BS 4
#define SEQ 4096
#define ROWS (BS * SEQ)   // 16384
#define SC 64
#define NC (SEQ / SC)     // 64

#define BARRIER() asm volatile("s_barrier" ::: "memory")
#define WAITV(n)  asm volatile("s_waitcnt vmcnt(" #n ")" ::: "memory")

__device__ __forceinline__ void gld_lds16(const half_t* g, char* l) {
  __builtin_amdgcn_global_load_lds((const __attribute__((address_space(1))) void*)g,
                                   (__attribute__((address_space(3))) void*)l, 16, 0, 0);
}

// ---------------- flags: detect all-zero weight matrices ----------------
__global__ void zero_flags(int* f) {
  if (threadIdx.x < 2) f[threadIdx.x] = 0;
}

__global__ __launch_bounds__(256) void detect_nz(const float* __restrict__ W0,
                                                 const float* __restrict__ W1,
                                                 int* __restrict__ flags) {
  const int which = blockIdx.x >> 8;
  const unsigned* w = (const unsigned*)(which ? W1 : W0);
  const int blk = blockIdx.x & 255;
  unsigned v = 0;
  const size_t base = (size_t)blk * 4096 + threadIdx.x;
#pragma unroll
  for (int i = 0; i < 16; ++i) v |= w[base + i * 256];
#pragma unroll
  for (int off = 32; off > 0; off >>= 1) v |= __shfl_down(v, off, 64);
  __shared__ unsigned sv[4];
  if ((threadIdx.x & 63) == 0) sv[threadIdx.x >> 6] = v;
  __syncthreads();
  if (threadIdx.x == 0) {
    v = sv[0] | sv[1] | sv[2] | sv[3];
    if (v) atomicOr(&flags[which], 1);
  }
}

// ---------------- softmax of (bias/32): one 1024-vector per bias, f32 ----------------
__global__ __launch_bounds__(256) void bias_softmax(const float* __restrict__ bqa,
                                                    const float* __restrict__ bka,
                                                    float* __restrict__ qwv,
                                                    float* __restrict__ kwv) {
  const float* b = blockIdx.x ? bka : bqa;
  float* o = blockIdx.x ? kwv : qwv;
  const int t = threadIdx.x;
  f32x4 v = *(const f32x4*)(b + t * 4);
  float x[4];
#pragma unroll
  for (int i = 0; i < 4; i++) x[i] = v[i] * 0.03125f;
  float mx = fmaxf(fmaxf(x[0], x[1]), fmaxf(x[2], x[3]));
#pragma unroll
  for (int off = 32; off > 0; off >>= 1) mx = fmaxf(mx, __shfl_xor(mx, off, 64));
  __shared__ float sm[4], ssum[4];
  const int wv = t >> 6, ln = t & 63;
  if (ln == 0) sm[wv] = mx;
  __syncthreads();
  mx = fmaxf(fmaxf(sm[0], sm[1]), fmaxf(sm[2], sm[3]));
  float e[4]; float s = 0.f;
#pragma unroll
  for (int i = 0; i < 4; i++) { e[i] = expf(x[i] - mx); s += e[i]; }
#pragma unroll
  for (int off = 32; off > 0; off >>= 1) s += __shfl_xor(s, off, 64);
  if (ln == 0) ssum[wv] = s;
  __syncthreads();
  s = ssum[0] + ssum[1] + ssum[2] + ssum[3];
  const float r = 1.0f / s;
  f32x4 ov;
#pragma unroll
  for (int i = 0; i < 4; i++) ov[i] = e[i] * r;
  *(f32x4*)(o + t * 4) = ov;
}

// ---------------- LayerNorm: fp32 in -> f16 out ----------------
__global__ __launch_bounds__(256) void ln_kernel(const float* __restrict__ x,
                                                 const float* __restrict__ gamma,
                                                 const float* __restrict__ beta,
                                                 half_t* __restrict__ h) {
  const int row = blockIdx.x;
  const int t = threadIdx.x;
  const float* xr = x + (size_t)row * D_MODEL + t * 4;
  f32x4 v = *(const f32x4*)xr;
  float s = v[0] + v[1] + v[2] + v[3];
  float q = v[0]*v[0] + v[1]*v[1] + v[2]*v[2] + v[3]*v[3];
#pragma unroll
  for (int off = 32; off > 0; off >>= 1) {
    s += __shfl_down(s, off, 64);
    q += __shfl_down(q, off, 64);
  }
  __shared__ float rs[4], rq[4];
  const int wv = t >> 6, ln = t & 63;
  if (ln == 0) { rs[wv] = s; rq[wv] = q; }
  __syncthreads();
  s = rs[0] + rs[1] + rs[2] + rs[3];
  q = rq[0] + rq[1] + rq[2] + rq[3];
  const float mu = s * (1.0f / D_MODEL);
  const float var = q * (1.0f / D_MODEL) - mu * mu;
  const float rstd = rsqrtf(var + 1e-5f);
  f32x4 g = *(const f32x4*)(gamma + t * 4);
  f32x4 b = *(const f32x4*)(beta + t * 4);
  f16x4 o;
#pragma unroll
  for (int i = 0; i < 4; i++) o[i] = (half_t)((v[i] - mu) * rstd * g[i] + b[i]);
  *(f16x4*)(h + (size_t)row * D_MODEL + t * 4) = o;
}

// ---------------- weight prepack: fp32 [K][N] -> f16 [N][K] ----------------
__global__ __launch_bounds__(256) void prep_w(const float* __restrict__ Wq,
                                              const float* __restrict__ Wk,
                                              const float* __restrict__ Wv,
                                              const float* __restrict__ Wqa,
                                              const float* __restrict__ Wka,
                                              half_t* __restrict__ wcat,
                                              half_t* __restrict__ wqa,
                                              half_t* __restrict__ wka) {
  const int b = blockIdx.x;
  const int mat = b >> 10;
  const int tile = b & 1023;
  const int tn = (tile & 31) * 32;
  const int tk = (tile >> 5) * 32;
  const float* W = mat == 0 ? Wq : mat == 1 ? Wk : mat == 2 ? Wv : mat == 3 ? Wqa : Wka;
  half_t* dst = mat < 3 ? wcat + (size_t)mat * D_MODEL * D_MODEL : (mat == 3 ? wqa : wka);
  __shared__ float tl[32][33];
  const int tx = threadIdx.x & 31, ty = threadIdx.x >> 5;
#pragma unroll
  for (int i = 0; i < 32; i += 8)
    tl[ty + i][tx] = W[(size_t)(tk + ty + i) * D_MODEL + tn + tx];
  __syncthreads();
#pragma unroll
  for (int i = 0; i < 32; i += 8)
    dst[(size_t)(tn + ty + i) * D_MODEL + tk + tx] = (half_t)tl[tx][ty + i];
}

__global__ __launch_bounds__(256) void copy_bias(const float* __restrict__ bq,
                                                 const float* __restrict__ bk,
                                                 const float* __restrict__ bv,
                                                 float* __restrict__ bcat) {
  const int i = blockIdx.x * 256 + threadIdx.x;
  if (i < 1024) bcat[i] = bq[i];
  else if (i < 2048) bcat[i] = bk[i - 1024];
  else if (i < 3072) bcat[i] = bv[i - 2048];
}

// ---------------- 256x256 8-phase MFMA GEMM (32x32x16), K=1024 fixed ----------------
// Wave tile 128x64 = 4 m-frags x 2 n-frags of 32x32; K-tile 64 = 4 k-steps.
// Per phase: one quadrant = 2 m-frags x 1 n-frag x 4 ksteps = 8 MFMA.
// A frag: row=l&31, k=(l>>5)*8+i.  D: col=l&31, row=(r&3)+8*(r>>2)+4*(l>>5).
// Stage slots (audited vs region last-reads Aα:P1 Bγ:P1 Bδ:P2 Aβ:P3):
//   P1:Bδ(b) P2:Aα(c) P3:Bγ(c) P4:Aβ(c)+w6 P5:Bδ(c) P6:Aα(d) P7:Bγ(d) P8:Aβ(d)+w6

#define SA2(buf, rb, kt) do { \
  gld_lds16(gA + (size_t)((rb) + wbA + r8) * lda + (size_t)(kt) * 64 + grn * 8, \
            smem + (buf)*65536 + ((rb) + wbA) * 128); \
  gld_lds16(gA + (size_t)((rb) + 128 + wbA + r8) * lda + (size_t)(kt) * 64 + grn * 8, \
            smem + (buf)*65536 + ((rb) + 128 + wbA) * 128); \
} while (0)

#define SB2(buf, gd, kt) do { \
  gld_lds16(gB + (size_t)((gd) + wbB + r8) * 1024 + (size_t)(kt) * 64 + grn * 8, \
            smem + (buf)*65536 + 32768 + ((gd) + wbB) * 128); \
  gld_lds16(gB + (size_t)((gd) + 128 + wbB + r8) * 1024 + (size_t)(kt) * 64 + grn * 8, \
            smem + (buf)*65536 + 32768 + ((gd) + 128 + wbB) * 128); \
} while (0)

#define LOAD_ALO(buf) do { \
  _Pragma("unroll") for (int _m = 0; _m < 2; ++_m) \
  _Pragma("unroll") for (int _k = 0; _k < 4; ++_k) \
    aFr[_m][_k] = *(const f16x8*)(smem + (buf)*65536 + rA + _m*4096 + cswk[_k]); \
} while (0)

#define LOAD_AHI(buf) do { \
  _Pragma("unroll") for (int _m = 0; _m < 2; ++_m) \
  _Pragma("unroll") for (int _k = 0; _k < 4; ++_k) \
    aHr[_m][_k] = *(const f16x8*)(smem + (buf)*65536 + rA + (2+_m)*4096 + cswk[_k]); \
} while (0)

#define LOAD_BN(dst, buf, nf) do { \
  _Pragma("unroll") for (int _k = 0; _k < 4; ++_k) \
    dst[_k] = *(const f16x8*)(smem + (buf)*65536 + 32768 + rB + (nf)*4096 + cswk[_k]); \
} while (0)

#define QUAD32(AA, BB, MOFF, NOFF) do { \
  __builtin_amdgcn_s_setprio(1); \
  _Pragma("unroll") for (int _k = 0; _k < 4; ++_k) \
  _Pragma("unroll") for (int _m = 0; _m < 2; ++_m) \
    acc[(MOFF)+_m][NOFF] = __builtin_amdgcn_mfma_f32_32x32x16_f16(AA[_m][_k], BB[_k], acc[(MOFF)+_m][NOFF], 0, 0, 0); \
  __builtin_amdgcn_s_setprio(0); \
} while (0)

__global__ __launch_bounds__(512, 2) void gemm8(const half_t* __restrict__ A, int lda,
                                                const half_t* __restrict__ Bt,
                                                const float* __restrict__ bias,
                                                half_t* __restrict__ C, int ldc,
                                                const int* skip) {
  if (skip && *skip == 0) return;
  extern __shared__ char smem[];
  const int t = threadIdx.x;
  const int ln = t & 63, wid = t >> 6;
  const int wm = wid >> 2, wn = wid & 3;

  const int gx = gridDim.x;
  const int nwg = gx * gridDim.y;
  const int orig = blockIdx.y * gx + blockIdx.x;
  const int swz = (orig & 7) * (nwg >> 3) + (orig >> 3);
  const int bx = swz % gx, by = swz / gx;
  const int n0 = bx * 256, m0 = by * 256;

  const int r8 = (t >> 3) & 7;
  const int grn = (t & 7) ^ r8;
  const int wbA = wid * 8;
  const int wbB = ((wid >> 2) << 6) + (wid & 3) * 8;
  const half_t* gA = A + (size_t)m0 * lda;
  const half_t* gB = Bt + (size_t)n0 * 1024;

  // fragment read geometry (32x32x16): row=l&31, k-granule = 2*ks + (l>>5)
  const int rA = (wm * 128 + (ln & 31)) * 128;
  const int rB = (wn * 64 + (ln & 31)) * 128;
  const int hi = ln >> 5;
  int cswk[4];
#pragma unroll
  for (int ks = 0; ks < 4; ++ks) cswk[ks] = ((2 * ks + hi) ^ (ln & 7)) << 4;

  f32x16 acc[4][2] = {};
  f16x8 aFr[2][4], aHr[2][4], bN0[4], bN1[4];

  // prologue: tile0 complete, tile1 Aα,Bγ,Aβ (Bδ(1) staged at i=0 P1)
  SA2(0, 0, 0); SB2(0, 0, 0); SA2(0, 64, 0); SB2(0, 32, 0);
  SA2(1, 0, 1); SB2(1, 0, 1); SA2(1, 64, 1);
  WAITV(6); BARRIER();

#pragma unroll 1
  for (int i = 0; i < 8; ++i) {
    const int kb = 2 * i + 1;
    const int kc = 2 * i + 2;
    const int kd = 2 * i + 3;
    const bool f = (i < 7);
    // ---- P1: read aLo+bN0 (buf0); stage Bδ(b); Q0 = aLo x n0
    LOAD_ALO(0); LOAD_BN(bN0, 0, 0);
    SB2(1, 32, kb);
    QUAD32(aFr, bN0, 0, 0); BARRIER();
    // ---- P2: read bN1; stage Aα(c); Q1 = aLo x n1
    LOAD_BN(bN1, 0, 1);
    if (f) SA2(0, 0, kc);
    QUAD32(aFr, bN1, 0, 1); BARRIER();
    // ---- P3: read aHi; stage Bγ(c); Q2 = aHi x n1
    LOAD_AHI(0);
    if (f) SB2(0, 0, kc);
    QUAD32(aHr, bN1, 2, 1); BARRIER();
    // ---- P4: stage Aβ(c); counted wait; Q3 = aHi x n0 (regs only)
    if (f) { SA2(0, 64, kc); WAITV(6); } else WAITV(0);
    QUAD32(aHr, bN0, 2, 0); BARRIER();
    // ---- P5: buf1
    LOAD_ALO(1); LOAD_BN(bN0, 1, 0);
    if (f) SB2(0, 32, kc);
    QUAD32(aFr, bN0, 0, 0); BARRIER();
    // ---- P6
    LOAD_BN(bN1, 1, 1);
    if (f) SA2(1, 0, kd);
    QUAD32(aFr, bN1, 0, 1); BARRIER();
    // ---- P7
    LOAD_AHI(1);
    if (f) SB2(1, 0, kd);
    QUAD32(aHr, bN1, 2, 1); BARRIER();
    // ---- P8
    if (f) { SA2(1, 64, kd); WAITV(6); }
    QUAD32(aHr, bN0, 2, 0); BARRIER();
  }

  // epilogue: D col=l&31, row=(r&3)+8*(r>>2)+4*(l>>5)
  const int cbase = n0 + wn * 64 + (ln & 31);
  const int rbase = m0 + wm * 128 + 4 * (ln >> 5);
#pragma unroll
  for (int mf = 0; mf < 4; ++mf)
#pragma unroll
    for (int nf = 0; nf < 2; ++nf) {
      const int col = cbase + nf * 32;
      const float bb = bias[col];
#pragma unroll
      for (int r = 0; r < 16; ++r) {
        const int row = rbase + mf * 32 + (r & 3) + 8 * (r >> 2);
        C[(size_t)row * ldc + col] = (half_t)(acc[mf][nf][r] + bb);
      }
    }
}

// ---------------- row softmax over D=1024, logits scaled 1/32 ----------------
__global__ __launch_bounds__(256) void softmax_k(const half_t* __restrict__ L,
                                                 half_t* __restrict__ O,
                                                 const int* skip) {
  if (skip && *skip == 0) return;
  const size_t row = blockIdx.x;
  const int t = threadIdx.x;
  f16x4 v = *(const f16x4*)(L + row * D_MODEL + t * 4);
  float x[4];
#pragma unroll
  for (int i = 0; i < 4; i++) x[i] = (float)v[i] * 0.03125f;
  float mx = fmaxf(fmaxf(x[0], x[1]), fmaxf(x[2], x[3]));
#pragma unroll
  for (int off = 32; off > 0; off >>= 1) mx = fmaxf(mx, __shfl_xor(mx, off, 64));
  __shared__ float sm[4], ssum[4];
  const int wv = t >> 6, ln = t & 63;
  if (ln == 0) sm[wv] = mx;
  __syncthreads();
  mx = fmaxf(fmaxf(sm[0], sm[1]), fmaxf(sm[2], sm[3]));
  float e[4]; float s = 0.f;
#pragma unroll
  for (int i = 0; i < 4; i++) { e[i] = expf(x[i] - mx); s += e[i]; }
#pragma unroll
  for (int off = 32; off > 0; off >>= 1) s += __shfl_xor(s, off, 64);
  if (ln == 0) ssum[wv] = s;
  __syncthreads();
  s = ssum[0] + ssum[1] + ssum[2] + ssum[3];
  const float r = 1.0f / s;
  f16x4 o;
#pragma unroll
  for (int i = 0; i < 4; i++) o[i] = (half_t)(e[i] * r);
  *(f16x4*)(O + row * D_MODEL + t * 4) = o;
}

// ---------------- cumsum pass 1: 2 d-elems/thread ----------------
__global__ __launch_bounds__(256) void cs_partial(const int* __restrict__ nz,
                                                  const float* __restrict__ wv,
                                                  const half_t* __restrict__ A, int ldA,
                                                  const half_t* __restrict__ B, int ldB,
                                                  float* __restrict__ part) {
  const int d = (blockIdx.x * 256 + threadIdx.x) * 2;
  const int c = blockIdx.y;
  const int bb = blockIdx.z;
  const size_t s0 = (size_t)bb * SEQ + (size_t)c * SC;
  const half_t* pa = A + s0 * ldA + d;
  const half_t* pb = B + s0 * ldB + d;
  f32x2 acc = {0.f, 0.f};
  if (*nz == 0) {
    const f32x2 w = *(const f32x2*)&wv[d];
#pragma unroll 8
    for (int s = 0; s < SC; s++) {
      f16x2 b = *(const f16x2*)&pb[(size_t)s * ldB];
      acc[0] += w[0] * (float)b[0];
      acc[1] += w[1] * (float)b[1];
    }
  } else {
#pragma unroll 8
    for (int s = 0; s < SC; s++) {
      f16x2 a = *(const f16x2*)&pa[(size_t)s * ldA];
      f16x2 b = *(const f16x2*)&pb[(size_t)s * ldB];
      acc[0] += (float)a[0] * (float)b[0];
      acc[1] += (float)a[1] * (float)b[1];
    }
  }
  *(f32x2*)&part[((size_t)bb * NC + c) * D_MODEL + d] = acc;
}

// ---------------- cumsum pass 1 for stage 2 (shortcut uses msum) ----------------
__global__ __launch_bounds__(256) void cs_partial2(const int* __restrict__ nz,
                                                   const float* __restrict__ wv,
                                                   const float* __restrict__ msum,
                                                   const half_t* __restrict__ A, int ldA,
                                                   const half_t* __restrict__ B, int ldB,
                                                   float* __restrict__ part) {
  const int d = (blockIdx.x * 256 + threadIdx.x) * 2;
  const int c = blockIdx.y;
  const int bb = blockIdx.z;
  const size_t idx = ((size_t)bb * NC + c) * D_MODEL + d;
  if (*nz == 0) {
    const f32x2 w = *(const f32x2*)&wv[d];
    const f32x2 m = *(const f32x2*)&msum[idx];
    f32x2 r = {w[0] * m[0], w[1] * m[1]};
    *(f32x2*)&part[idx] = r;
    return;
  }
  const size_t s0 = (size_t)bb * SEQ + (size_t)c * SC;
  const half_t* pa = A + s0 * ldA + d;
  const half_t* pb = B + s0 * ldB + d;
  f32x2 acc = {0.f, 0.f};
#pragma unroll 8
  for (int s = 0; s < SC; s++) {
    f16x2 a = *(const f16x2*)&pa[(size_t)s * ldA];
    f16x2 b = *(const f16x2*)&pb[(size_t)s * ldB];
    acc[0] += (float)a[0] * (float)b[0];
    acc[1] += (float)a[1] * (float)b[1];
  }
  *(f32x2*)&part[idx] = acc;
}

// ---------------- cumsum pass 2: 2 d-elems/thread ----------------
template <bool HALF_OUT>
__global__ __launch_bounds__(256) void cs_apply(const int* __restrict__ nz,
                                                const float* __restrict__ wv,
                                                const half_t* __restrict__ A, int ldA,
                                                const half_t* __restrict__ B, int ldB,
                                                const half_t* __restrict__ Cm, int ldC,
                                                const float* __restrict__ part,
                                                float* __restrict__ msum,
                                                half_t* __restrict__ OH,
                                                float* __restrict__ OF) {
  const int d = (blockIdx.x * 256 + threadIdx.x) * 2;
  const int c = blockIdx.y;
  const int bb = blockIdx.z;
  f32x2 acc = {0.f, 0.f};
  for (int cc = 0; cc < c; cc++) {
    f32x2 p = *(const f32x2*)&part[((size_t)bb * NC + cc) * D_MODEL + d];
    acc[0] += p[0]; acc[1] += p[1];
  }
  const size_t s0 = (size_t)bb * SEQ + (size_t)c * SC;
  f32x2 ms = {0.f, 0.f};
  const int nzv = *nz;
  f32x2 w = {0.f, 0.f};
  if (nzv == 0) w = *(const f32x2*)&wv[d];
#pragma unroll 4
  for (int s = 0; s < SC; s++) {
    const size_t sg = s0 + s;
    if (nzv == 0) {
      f16x2 b = *(const f16x2*)&B[sg * ldB + d];
      acc[0] += w[0] * (float)b[0];
      acc[1] += w[1] * (float)b[1];
    } else {
      f16x2 a = *(const f16x2*)&A[sg * ldA + d];
      f16x2 b = *(const f16x2*)&B[sg * ldB + d];
      acc[0] += (float)a[0] * (float)b[0];
      acc[1] += (float)a[1] * (float)b[1];
    }
    const float rinv = 1.0f / (float)(c * SC + s + 1);
    f16x2 cm = *(const f16x2*)&Cm[sg * ldC + d];
    const float m0 = acc[0] * rinv * (float)cm[0];
    const float m1 = acc[1] * rinv * (float)cm[1];
    ms[0] += m0; ms[1] += m1;
    if (HALF_OUT) {
      f16x2 o; o[0] = (half_t)m0; o[1] = (half_t)m1;
      *(f16x2*)&OH[sg * D_MODEL + d] = o;
    } else {
      f32x2 o = {m0, m1};
      *(f32x2*)&OF[sg * D_MODEL + d] = o;
    }
  }
  if (msum) *(f32x2*)&msum[((size_t)bb * NC + c) * D_MODEL + d] = ms;
}

extern "C" void kernel_launch(void* const* d_in, const int* in_sizes, int n_in,
                              void* d_out, int out_size, void* d_ws, size_t ws_size,
                              hipStream_t stream) {
  const float* x     = (const float*)d_in[0];
  const float* Wq    = (const float*)d_in[2];
  const float* bq    = (const float*)d_in[3];
  const float* Wqa   = (const float*)d_in[4];
  const float* bqa   = (const float*)d_in[5];
  const float* Wk    = (const float*)d_in[6];
  const float* bk    = (const float*)d_in[7];
  const float* Wka   = (const float*)d_in[8];
  const float* bka   = (const float*)d_in[9];
  const float* Wv    = (const float*)d_in[10];
  const float* bv    = (const float*)d_in[11];
  const float* gamma = (const float*)d_in[12];
  const float* beta  = (const float*)d_in[13];
  float* out = (float*)d_out;

  char* ws = (char*)d_ws;
  const size_t MB = 1024 * 1024;
  half_t* h16    = (half_t*)(ws + 0);         // 32MB: h, later reused as mixed16
  half_t* qkv16  = (half_t*)(ws + 32 * MB);   // 96MB: [16384][3072] q|k|v
  half_t* logits = (half_t*)(ws + 128 * MB);  // 32MB
  half_t* wcat   = (half_t*)(ws + 160 * MB);  // 6MB (dead after gemm1)
  half_t* wqa16  = (half_t*)(ws + 166 * MB);  // 2MB
  half_t* wka16  = (half_t*)(ws + 168 * MB);  // 2MB
  float*  bcat   = (float*)(ws + 170 * MB);   // 12KB
  // part/msum live in the wcat region (only used after gemm1, wcat dead then)
  float*  part   = (float*)(ws + 160 * MB);          // 1MB  [BS][NC=64][1024]
  float*  msum   = (float*)(ws + 161 * MB);          // 1MB
  float*  qwv    = (float*)(ws + 170 * MB + 64 * 1024);  // 4KB
  float*  kwv    = (float*)(ws + 170 * MB + 68 * 1024);  // 4KB
  int*    flags  = (int*)(ws + 170 * MB + 72 * 1024);    // 8B

  half_t* q16 = qkv16;            // lda 3072
  half_t* k16 = qkv16 + 1024;
  half_t* v16 = qkv16 + 2048;
  half_t* mixed16 = h16;
  half_t* sw = logits;

  hipFuncSetAttribute((const void*)gemm8, hipFuncAttributeMaxDynamicSharedMemorySize, 131072);

  zero_flags<<<1, 64, 0, stream>>>(flags);
  detect_nz<<<512, 256, 0, stream>>>(Wqa, Wka, flags);
  bias_softmax<<<2, 256, 0, stream>>>(bqa, bka, qwv, kwv);
  prep_w<<<5120, 256, 0, stream>>>(Wq, Wk, Wv, Wqa, Wka, wcat, wqa16, wka16);
  copy_bias<<<12, 256, 0, stream>>>(bq, bk, bv, bcat);
  ln_kernel<<<ROWS, 256, 0, stream>>>(x, gamma, beta, h16);
  // q|k|v = h @ [Wq|Wk|Wv] + b   (M=16384, N=3072, K=1024)
  gemm8<<<dim3(12, 64), 512, 131072, stream>>>(h16, 1024, wcat, bcat, qkv16, 3072, nullptr);
  // logits = q @ Wqa + bqa  (skipped when Wqa == 0)
  gemm8<<<dim3(4, 64), 512, 131072, stream>>>(q16, 3072, wqa16, bqa, logits, 1024, flags);
  softmax_k<<<ROWS, 256, 0, stream>>>(logits, sw, flags);
  // mixed = (cumsum(qw.*q)/scale) .* k
  cs_partial<<<dim3(2, NC, BS), 256, 0, stream>>>(flags, qwv, sw, 1024, q16, 3072, part);
  cs_apply<true><<<dim3(2, NC, BS), 256, 0, stream>>>(flags, qwv, sw, 1024, q16, 3072,
                                                      k16, 3072, part, msum, mixed16, nullptr);
  // logits = mixed @ Wka + bka  (skipped when Wka == 0)
  gemm8<<<dim3(4, 64), 512, 131072, stream>>>(mixed16, 1024, wka16, bka, logits, 1024, flags + 1);
  softmax_k<<<ROWS, 256, 0, stream>>>(logits, sw, flags + 1);
  // out = (cumsum(kw.*mixed)/scale) .* v
  cs_partial2<<<dim3(2, NC, BS), 256, 0, stream>>>(flags + 1, kwv, msum, sw, 1024,
                                                   mixed16, 1024, part);
  cs_apply<false><<<dim3(2, NC, BS), 256, 0, stream>>>(flags + 1, kwv, sw, 1024, mixed16, 1024,
                                                       v16, 3072, part, nullptr, nullptr, out);
}

// Round 7
// 264.966 us; speedup vs baseline: 1.0804x; 1.0804x over previous
//
#include <hip/hip_runtime.h>

typedef _Float16 half_t;
typedef _Float16 f16x8 __attribute__((ext_vector_type(8)));
typedef _Float16 f16x4 __attribute__((ext_vector_type(4)));
typedef float f32x4 __attribute__((ext_vector_type(4)));

#define D_MODEL 1024
#define BS 4
#define SEQ 4096
#define ROWS (BS * SEQ)   // 16384
#define SC 32
#define NC (SEQ / SC)     // 128

#define BARRIER() asm volatile("s_barrier" ::: "memory")
#define WAITV(n)  asm volatile("s_waitcnt vmcnt(" #n ")" ::: "memory")

__device__ __forceinline__ void gld_lds16(const half_t* g, char* l) {
  __builtin_amdgcn_global_load_lds((const __attribute__((address_space(1))) void*)g,
                                   (__attribute__((address_space(3))) void*)l, 16, 0, 0);
}

// ---------------- flags: detect all-zero weight matrices ----------------
__global__ void zero_flags(int* f) {
  if (threadIdx.x < 2) f[threadIdx.x] = 0;
}

__global__ __launch_bounds__(256) void detect_nz(const float* __restrict__ W0,
                                                 const float* __restrict__ W1,
                                                 int* __restrict__ flags) {
  const int which = blockIdx.x >> 8;
  const unsigned* w = (const unsigned*)(which ? W1 : W0);
  const int blk = blockIdx.x & 255;
  unsigned v = 0;
  const size_t base = (size_t)blk * 4096 + threadIdx.x;
#pragma unroll
  for (int i = 0; i < 16; ++i) v |= w[base + i * 256];
#pragma unroll
  for (int off = 32; off > 0; off >>= 1) v |= __shfl_down(v, off, 64);
  __shared__ unsigned sv[4];
  if ((threadIdx.x & 63) == 0) sv[threadIdx.x >> 6] = v;
  __syncthreads();
  if (threadIdx.x == 0) {
    v = sv[0] | sv[1] | sv[2] | sv[3];
    if (v) atomicOr(&flags[which], 1);
  }
}

// ---------------- softmax of (bias/32): one 1024-vector per bias, f32 ----------------
__global__ __launch_bounds__(256) void bias_softmax(const float* __restrict__ bqa,
                                                    const float* __restrict__ bka,
                                                    float* __restrict__ qwv,
                                                    float* __restrict__ kwv) {
  const float* b = blockIdx.x ? bka : bqa;
  float* o = blockIdx.x ? kwv : qwv;
  const int t = threadIdx.x;
  f32x4 v = *(const f32x4*)(b + t * 4);
  float x[4];
#pragma unroll
  for (int i = 0; i < 4; i++) x[i] = v[i] * 0.03125f;
  float mx = fmaxf(fmaxf(x[0], x[1]), fmaxf(x[2], x[3]));
#pragma unroll
  for (int off = 32; off > 0; off >>= 1) mx = fmaxf(mx, __shfl_xor(mx, off, 64));
  __shared__ float sm[4], ssum[4];
  const int wv = t >> 6, ln = t & 63;
  if (ln == 0) sm[wv] = mx;
  __syncthreads();
  mx = fmaxf(fmaxf(sm[0], sm[1]), fmaxf(sm[2], sm[3]));
  float e[4]; float s = 0.f;
#pragma unroll
  for (int i = 0; i < 4; i++) { e[i] = expf(x[i] - mx); s += e[i]; }
#pragma unroll
  for (int off = 32; off > 0; off >>= 1) s += __shfl_xor(s, off, 64);
  if (ln == 0) ssum[wv] = s;
  __syncthreads();
  s = ssum[0] + ssum[1] + ssum[2] + ssum[3];
  const float r = 1.0f / s;
  f32x4 ov;
#pragma unroll
  for (int i = 0; i < 4; i++) ov[i] = e[i] * r;
  *(f32x4*)(o + t * 4) = ov;
}

// ---------------- LayerNorm: fp32 in -> f16 out ----------------
__global__ __launch_bounds__(256) void ln_kernel(const float* __restrict__ x,
                                                 const float* __restrict__ gamma,
                                                 const float* __restrict__ beta,
                                                 half_t* __restrict__ h) {
  const int row = blockIdx.x;
  const int t = threadIdx.x;
  const float* xr = x + (size_t)row * D_MODEL + t * 4;
  f32x4 v = *(const f32x4*)xr;
  float s = v[0] + v[1] + v[2] + v[3];
  float q = v[0]*v[0] + v[1]*v[1] + v[2]*v[2] + v[3]*v[3];
#pragma unroll
  for (int off = 32; off > 0; off >>= 1) {
    s += __shfl_down(s, off, 64);
    q += __shfl_down(q, off, 64);
  }
  __shared__ float rs[4], rq[4];
  const int wv = t >> 6, ln = t & 63;
  if (ln == 0) { rs[wv] = s; rq[wv] = q; }
  __syncthreads();
  s = rs[0] + rs[1] + rs[2] + rs[3];
  q = rq[0] + rq[1] + rq[2] + rq[3];
  const float mu = s * (1.0f / D_MODEL);
  const float var = q * (1.0f / D_MODEL) - mu * mu;
  const float rstd = rsqrtf(var + 1e-5f);
  f32x4 g = *(const f32x4*)(gamma + t * 4);
  f32x4 b = *(const f32x4*)(beta + t * 4);
  f16x4 o;
#pragma unroll
  for (int i = 0; i < 4; i++) o[i] = (half_t)((v[i] - mu) * rstd * g[i] + b[i]);
  *(f16x4*)(h + (size_t)row * D_MODEL + t * 4) = o;
}

// ---------------- weight prepack: fp32 [K][N] -> f16 [N][K] ----------------
__global__ __launch_bounds__(256) void prep_w(const float* __restrict__ Wq,
                                              const float* __restrict__ Wk,
                                              const float* __restrict__ Wv,
                                              const float* __restrict__ Wqa,
                                              const float* __restrict__ Wka,
                                              half_t* __restrict__ wcat,
                                              half_t* __restrict__ wqa,
                                              half_t* __restrict__ wka) {
  const int b = blockIdx.x;
  const int mat = b >> 10;
  const int tile = b & 1023;
  const int tn = (tile & 31) * 32;
  const int tk = (tile >> 5) * 32;
  const float* W = mat == 0 ? Wq : mat == 1 ? Wk : mat == 2 ? Wv : mat == 3 ? Wqa : Wka;
  half_t* dst = mat < 3 ? wcat + (size_t)mat * D_MODEL * D_MODEL : (mat == 3 ? wqa : wka);
  __shared__ float tl[32][33];
  const int tx = threadIdx.x & 31, ty = threadIdx.x >> 5;
#pragma unroll
  for (int i = 0; i < 32; i += 8)
    tl[ty + i][tx] = W[(size_t)(tk + ty + i) * D_MODEL + tn + tx];
  __syncthreads();
#pragma unroll
  for (int i = 0; i < 32; i += 8)
    dst[(size_t)(tn + ty + i) * D_MODEL + tk + tx] = (half_t)tl[tx][ty + i];
}

__global__ __launch_bounds__(256) void copy_bias(const float* __restrict__ bq,
                                                 const float* __restrict__ bk,
                                                 const float* __restrict__ bv,
                                                 float* __restrict__ bcat) {
  const int i = blockIdx.x * 256 + threadIdx.x;
  if (i < 1024) bcat[i] = bq[i];
  else if (i < 2048) bcat[i] = bk[i - 1024];
  else if (i < 3072) bcat[i] = bv[i - 2048];
}

// ---------------- 256x256 8-phase MFMA GEMM (16x16x32), K=1024 fixed ----------------
// R5 version: one barrier per phase (end only); stage slots:
//   P1:Bδ(b) P2:Aα(c) P3:Bγ(c) P4:Aβ(c)+w6 P5:Bδ(c) P6:Aα(d) P7:Bγ(d) P8:Aβ(d)+w6

#define SA2(buf, rb, kt) do { \
  gld_lds16(gA + (size_t)((rb) + wbA + r8) * lda + (size_t)(kt) * 64 + grn * 8, \
            smem + (buf)*65536 + ((rb) + wbA) * 128); \
  gld_lds16(gA + (size_t)((rb) + 128 + wbA + r8) * lda + (size_t)(kt) * 64 + grn * 8, \
            smem + (buf)*65536 + ((rb) + 128 + wbA) * 128); \
} while (0)

#define SB2(buf, gd, kt) do { \
  gld_lds16(gB + (size_t)((gd) + wbB + r8) * 1024 + (size_t)(kt) * 64 + grn * 8, \
            smem + (buf)*65536 + 32768 + ((gd) + wbB) * 128); \
  gld_lds16(gB + (size_t)((gd) + 128 + wbB + r8) * 1024 + (size_t)(kt) * 64 + grn * 8, \
            smem + (buf)*65536 + 32768 + ((gd) + 128 + wbB) * 128); \
} while (0)

#define LOAD_A(buf, base) do { \
  _Pragma("unroll") for (int _fm = 0; _fm < 4; ++_fm) { \
    aF[_fm][0] = *(const f16x8*)(smem + (buf)*65536 + rA + gsw0 + ((base)+_fm)*2048); \
    aF[_fm][1] = *(const f16x8*)(smem + (buf)*65536 + rA + gsw1 + ((base)+_fm)*2048); \
  } \
} while (0)

#define LOAD_B(dst, buf, base) do { \
  _Pragma("unroll") for (int _fn = 0; _fn < 2; ++_fn) { \
    dst[_fn][0] = *(const f16x8*)(smem + (buf)*65536 + 32768 + rB + gsw0 + ((base)+_fn)*2048); \
    dst[_fn][1] = *(const f16x8*)(smem + (buf)*65536 + 32768 + rB + gsw1 + ((base)+_fn)*2048); \
  } \
} while (0)

#define QUAD(BR, MOFF, NOFF) do { \
  __builtin_amdgcn_s_setprio(1); \
  _Pragma("unroll") for (int _fm = 0; _fm < 4; ++_fm) \
  _Pragma("unroll") for (int _fn = 0; _fn < 2; ++_fn) { \
    acc[(MOFF)+_fm][(NOFF)+_fn] = __builtin_amdgcn_mfma_f32_16x16x32_f16(aF[_fm][0], BR[_fn][0], acc[(MOFF)+_fm][(NOFF)+_fn], 0, 0, 0); \
    acc[(MOFF)+_fm][(NOFF)+_fn] = __builtin_amdgcn_mfma_f32_16x16x32_f16(aF[_fm][1], BR[_fn][1], acc[(MOFF)+_fm][(NOFF)+_fn], 0, 0, 0); \
  } \
  __builtin_amdgcn_s_setprio(0); \
} while (0)

__global__ __launch_bounds__(512, 2) void gemm8(const half_t* __restrict__ A, int lda,
                                                const half_t* __restrict__ Bt,
                                                const float* __restrict__ bias,
                                                half_t* __restrict__ C, int ldc,
                                                const int* skip) {
  if (skip && *skip == 0) return;
  extern __shared__ char smem[];
  const int t = threadIdx.x;
  const int ln = t & 63, wid = t >> 6;
  const int wm = wid >> 2, wn = wid & 3;

  const int gx = gridDim.x;
  const int nwg = gx * gridDim.y;
  const int orig = blockIdx.y * gx + blockIdx.x;
  const int swz = (orig & 7) * (nwg >> 3) + (orig >> 3);
  const int bx = swz % gx, by = swz / gx;
  const int n0 = bx * 256, m0 = by * 256;

  const int r8 = (t >> 3) & 7;
  const int grn = (t & 7) ^ r8;
  const int wbA = wid * 8;
  const int wbB = ((wid >> 2) << 6) + (wid & 3) * 8;
  const half_t* gA = A + (size_t)m0 * lda;
  const half_t* gB = Bt + (size_t)n0 * 1024;

  const int rA = (wm * 128 + (ln & 15)) * 128;
  const int rB = (wn * 64 + (ln & 15)) * 128;
  const int gsw0 = (((ln >> 4)) ^ (ln & 7)) << 4;
  const int gsw1 = ((4 | (ln >> 4)) ^ (ln & 7)) << 4;

  f32x4 acc[8][4] = {};
  f16x8 aF[4][2], bL[2][2], bH[2][2];

  // prologue: tile0 complete, tile1 Aα,Bγ,Aβ (Bδ(1) staged at i=0 P1)
  SA2(0, 0, 0); SB2(0, 0, 0); SA2(0, 64, 0); SB2(0, 32, 0);
  SA2(1, 0, 1); SB2(1, 0, 1); SA2(1, 64, 1);
  WAITV(6); BARRIER();

#pragma unroll 1
  for (int i = 0; i < 8; ++i) {
    const int kb = 2 * i + 1;
    const int kc = 2 * i + 2;
    const int kd = 2 * i + 3;
    const bool f = (i < 7);
    // ---- P1: read aLow+bL+bH (buf0); stage Bδ(b); Q0
    LOAD_A(0, 0); LOAD_B(bL, 0, 0); LOAD_B(bH, 0, 2);
    SB2(1, 32, kb);
    QUAD(bL, 0, 0); BARRIER();
    // ---- P2: stage Aα(c); Q1 (operands already in regs)
    if (f) SA2(0, 0, kc);
    QUAD(bH, 0, 2); BARRIER();
    // ---- P3: read aHigh(buf0); stage Bγ(c); Q2
    LOAD_A(0, 4);
    if (f) SB2(0, 0, kc);
    QUAD(bH, 4, 2); BARRIER();
    // ---- P4: stage Aβ(c); counted wait; Q3 (ready)
    if (f) { SA2(0, 64, kc); WAITV(6); } else WAITV(0);
    QUAD(bL, 4, 0); BARRIER();
    // ---- P5: reads (buf1); stage Bδ(c); Q0
    LOAD_A(1, 0); LOAD_B(bL, 1, 0); LOAD_B(bH, 1, 2);
    if (f) SB2(0, 32, kc);
    QUAD(bL, 0, 0); BARRIER();
    // ---- P6: stage Aα(d); Q1
    if (f) SA2(1, 0, kd);
    QUAD(bH, 0, 2); BARRIER();
    // ---- P7: read aHigh(buf1); stage Bγ(d); Q2
    LOAD_A(1, 4);
    if (f) SB2(1, 0, kd);
    QUAD(bH, 4, 2); BARRIER();
    // ---- P8: stage Aβ(d); counted wait; Q3
    if (f) { SA2(1, 64, kd); WAITV(6); }
    QUAD(bL, 4, 0); BARRIER();
  }

  const int r0 = m0 + wm * 128 + ((ln >> 4) << 2);
  const int c0 = n0 + wn * 64 + (ln & 15);
  float bb[4];
#pragma unroll
  for (int fn = 0; fn < 4; ++fn) bb[fn] = bias[c0 + fn * 16];
#pragma unroll
  for (int fm = 0; fm < 8; ++fm)
#pragma unroll
    for (int fn = 0; fn < 4; ++fn) {
      const int col = c0 + fn * 16;
      const int row = r0 + fm * 16;
#pragma unroll
      for (int r = 0; r < 4; ++r)
        C[(size_t)(row + r) * ldc + col] = (half_t)(acc[fm][fn][r] + bb[fn]);
    }
}

// ---------------- row softmax over D=1024, logits scaled 1/32 ----------------
__global__ __launch_bounds__(256) void softmax_k(const half_t* __restrict__ L,
                                                 half_t* __restrict__ O,
                                                 const int* skip) {
  if (skip && *skip == 0) return;
  const size_t row = blockIdx.x;
  const int t = threadIdx.x;
  f16x4 v = *(const f16x4*)(L + row * D_MODEL + t * 4);
  float x[4];
#pragma unroll
  for (int i = 0; i < 4; i++) x[i] = (float)v[i] * 0.03125f;
  float mx = fmaxf(fmaxf(x[0], x[1]), fmaxf(x[2], x[3]));
#pragma unroll
  for (int off = 32; off > 0; off >>= 1) mx = fmaxf(mx, __shfl_xor(mx, off, 64));
  __shared__ float sm[4], ssum[4];
  const int wv = t >> 6, ln = t & 63;
  if (ln == 0) sm[wv] = mx;
  __syncthreads();
  mx = fmaxf(fmaxf(sm[0], sm[1]), fmaxf(sm[2], sm[3]));
  float e[4]; float s = 0.f;
#pragma unroll
  for (int i = 0; i < 4; i++) { e[i] = expf(x[i] - mx); s += e[i]; }
#pragma unroll
  for (int off = 32; off > 0; off >>= 1) s += __shfl_xor(s, off, 64);
  if (ln == 0) ssum[wv] = s;
  __syncthreads();
  s = ssum[0] + ssum[1] + ssum[2] + ssum[3];
  const float r = 1.0f / s;
  f16x4 o;
#pragma unroll
  for (int i = 0; i < 4; i++) o[i] = (half_t)(e[i] * r);
  *(f16x4*)(O + row * D_MODEL + t * 4) = o;
}

// ---------------- cumsum pass 1: 8 d-elems/thread, f16x8 loads ----------------
__global__ __launch_bounds__(128) void cs_partial(const int* __restrict__ nz,
                                                  const float* __restrict__ wv,
                                                  const half_t* __restrict__ A, int ldA,
                                                  const half_t* __restrict__ B, int ldB,
                                                  float* __restrict__ part) {
  const int d = threadIdx.x * 8;
  const int c = blockIdx.y;
  const int bb = blockIdx.z;
  const size_t s0 = (size_t)bb * SEQ + (size_t)c * SC;
  const half_t* pa = A + s0 * ldA + d;
  const half_t* pb = B + s0 * ldB + d;
  float acc[8] = {};
  if (*nz == 0) {
    float w[8];
    *(f32x4*)&w[0] = *(const f32x4*)&wv[d];
    *(f32x4*)&w[4] = *(const f32x4*)&wv[d + 4];
#pragma unroll 4
    for (int s = 0; s < SC; s++) {
      f16x8 b = *(const f16x8*)&pb[(size_t)s * ldB];
#pragma unroll
      for (int j = 0; j < 8; j++) acc[j] += w[j] * (float)b[j];
    }
  } else {
#pragma unroll 4
    for (int s = 0; s < SC; s++) {
      f16x8 a = *(const f16x8*)&pa[(size_t)s * ldA];
      f16x8 b = *(const f16x8*)&pb[(size_t)s * ldB];
#pragma unroll
      for (int j = 0; j < 8; j++) acc[j] += (float)a[j] * (float)b[j];
    }
  }
  float* pp = &part[((size_t)bb * NC + c) * D_MODEL + d];
  *(f32x4*)pp = *(f32x4*)&acc[0];
  *(f32x4*)(pp + 4) = *(f32x4*)&acc[4];
}

// ---------------- cumsum pass 1 for stage 2 (shortcut uses msum) ----------------
__global__ __launch_bounds__(128) void cs_partial2(const int* __restrict__ nz,
                                                   const float* __restrict__ wv,
                                                   const float* __restrict__ msum,
                                                   const half_t* __restrict__ A, int ldA,
                                                   const half_t* __restrict__ B, int ldB,
                                                   float* __restrict__ part) {
  const int d = threadIdx.x * 8;
  const int c = blockIdx.y;
  const int bb = blockIdx.z;
  const size_t idx = ((size_t)bb * NC + c) * D_MODEL + d;
  if (*nz == 0) {
    f32x4 w0 = *(const f32x4*)&wv[d], w1 = *(const f32x4*)&wv[d + 4];
    f32x4 m0 = *(const f32x4*)&msum[idx], m1 = *(const f32x4*)&msum[idx + 4];
#pragma unroll
    for (int j = 0; j < 4; j++) { m0[j] *= w0[j]; m1[j] *= w1[j]; }
    *(f32x4*)&part[idx] = m0;
    *(f32x4*)&part[idx + 4] = m1;
    return;
  }
  const size_t s0 = (size_t)bb * SEQ + (size_t)c * SC;
  const half_t* pa = A + s0 * ldA + d;
  const half_t* pb = B + s0 * ldB + d;
  float acc[8] = {};
#pragma unroll 4
  for (int s = 0; s < SC; s++) {
    f16x8 a = *(const f16x8*)&pa[(size_t)s * ldA];
    f16x8 b = *(const f16x8*)&pb[(size_t)s * ldB];
#pragma unroll
    for (int j = 0; j < 8; j++) acc[j] += (float)a[j] * (float)b[j];
  }
  *(f32x4*)&part[idx] = *(f32x4*)&acc[0];
  *(f32x4*)&part[idx + 4] = *(f32x4*)&acc[4];
}

// ---------------- cumsum pass 2: 8 d-elems/thread ----------------
template <bool HALF_OUT>
__global__ __launch_bounds__(128) void cs_apply(const int* __restrict__ nz,
                                                const float* __restrict__ wv,
                                                const half_t* __restrict__ A, int ldA,
                                                const half_t* __restrict__ B, int ldB,
                                                const half_t* __restrict__ Cm, int ldC,
                                                const float* __restrict__ part,
                                                float* __restrict__ msum,
                                                half_t* __restrict__ OH,
                                                float* __restrict__ OF) {
  const int d = threadIdx.x * 8;
  const int c = blockIdx.y;
  const int bb = blockIdx.z;
  float acc[8] = {};
  for (int cc = 0; cc < c; cc++) {
    const float* pp = &part[((size_t)bb * NC + cc) * D_MODEL + d];
    f32x4 p0 = *(const f32x4*)pp, p1 = *(const f32x4*)(pp + 4);
#pragma unroll
    for (int j = 0; j < 4; j++) { acc[j] += p0[j]; acc[4 + j] += p1[j]; }
  }
  const size_t s0 = (size_t)bb * SEQ + (size_t)c * SC;
  float ms[8] = {};
  if (*nz == 0) {
    float w[8];
    *(f32x4*)&w[0] = *(const f32x4*)&wv[d];
    *(f32x4*)&w[4] = *(const f32x4*)&wv[d + 4];
#pragma unroll 4
    for (int s = 0; s < SC; s++) {
      const size_t sg = s0 + s;
      f16x8 b = *(const f16x8*)&B[sg * ldB + d];
      f16x8 cm = *(const f16x8*)&Cm[sg * ldC + d];
      const float rinv = 1.0f / (float)(c * SC + s + 1);
      float m[8];
#pragma unroll
      for (int j = 0; j < 8; j++) {
        acc[j] += w[j] * (float)b[j];
        m[j] = acc[j] * rinv * (float)cm[j];
        ms[j] += m[j];
      }
      if (HALF_OUT) {
        f16x8 o;
#pragma unroll
        for (int j = 0; j < 8; j++) o[j] = (half_t)m[j];
        *(f16x8*)&OH[sg * D_MODEL + d] = o;
      } else {
        *(f32x4*)&OF[sg * D_MODEL + d] = *(f32x4*)&m[0];
        *(f32x4*)&OF[sg * D_MODEL + d + 4] = *(f32x4*)&m[4];
      }
    }
  } else {
#pragma unroll 4
    for (int s = 0; s < SC; s++) {
      const size_t sg = s0 + s;
      f16x8 a = *(const f16x8*)&A[sg * ldA + d];
      f16x8 b = *(const f16x8*)&B[sg * ldB + d];
      f16x8 cm = *(const f16x8*)&Cm[sg * ldC + d];
      const float rinv = 1.0f / (float)(c * SC + s + 1);
      float m[8];
#pragma unroll
      for (int j = 0; j < 8; j++) {
        acc[j] += (float)a[j] * (float)b[j];
        m[j] = acc[j] * rinv * (float)cm[j];
        ms[j] += m[j];
      }
      if (HALF_OUT) {
        f16x8 o;
#pragma unroll
        for (int j = 0; j < 8; j++) o[j] = (half_t)m[j];
        *(f16x8*)&OH[sg * D_MODEL + d] = o;
      } else {
        *(f32x4*)&OF[sg * D_MODEL + d] = *(f32x4*)&m[0];
        *(f32x4*)&OF[sg * D_MODEL + d + 4] = *(f32x4*)&m[4];
      }
    }
  }
  if (msum) {
    float* mp = &msum[((size_t)bb * NC + c) * D_MODEL + d];
    *(f32x4*)mp = *(f32x4*)&ms[0];
    *(f32x4*)(mp + 4) = *(f32x4*)&ms[4];
  }
}

extern "C" void kernel_launch(void* const* d_in, const int* in_sizes, int n_in,
                              void* d_out, int out_size, void* d_ws, size_t ws_size,
                              hipStream_t stream) {
  const float* x     = (const float*)d_in[0];
  const float* Wq    = (const float*)d_in[2];
  const float* bq    = (const float*)d_in[3];
  const float* Wqa   = (const float*)d_in[4];
  const float* bqa   = (const float*)d_in[5];
  const float* Wk    = (const float*)d_in[6];
  const float* bk    = (const float*)d_in[7];
  const float* Wka   = (const float*)d_in[8];
  const float* bka   = (const float*)d_in[9];
  const float* Wv    = (const float*)d_in[10];
  const float* bv    = (const float*)d_in[11];
  const float* gamma = (const float*)d_in[12];
  const float* beta  = (const float*)d_in[13];
  float* out = (float*)d_out;

  char* ws = (char*)d_ws;
  const size_t MB = 1024 * 1024;
  half_t* h16    = (half_t*)(ws + 0);         // 32MB: h, later reused as mixed16
  half_t* qkv16  = (half_t*)(ws + 32 * MB);   // 96MB: [16384][3072] q|k|v
  half_t* logits = (half_t*)(ws + 128 * MB);  // 32MB
  half_t* wcat   = (half_t*)(ws + 160 * MB);  // 6MB (dead after gemm1)
  half_t* wqa16  = (half_t*)(ws + 166 * MB);  // 2MB
  half_t* wka16  = (half_t*)(ws + 168 * MB);  // 2MB
  float*  bcat   = (float*)(ws + 170 * MB);   // 12KB
  // part/msum live in the dead-wcat region (used only after gemm1)
  float*  part   = (float*)(ws + 160 * MB);          // 2MB [BS][NC=128][1024] f32
  float*  msum   = (float*)(ws + 162 * MB);          // 2MB
  float*  qwv    = (float*)(ws + 170 * MB + 64 * 1024);  // 4KB
  float*  kwv    = (float*)(ws + 170 * MB + 68 * 1024);  // 4KB
  int*    flags  = (int*)(ws + 170 * MB + 72 * 1024);    // 8B

  half_t* q16 = qkv16;            // lda 3072
  half_t* k16 = qkv16 + 1024;
  half_t* v16 = qkv16 + 2048;
  half_t* mixed16 = h16;
  half_t* sw = logits;

  hipFuncSetAttribute((const void*)gemm8, hipFuncAttributeMaxDynamicSharedMemorySize, 131072);

  zero_flags<<<1, 64, 0, stream>>>(flags);
  detect_nz<<<512, 256, 0, stream>>>(Wqa, Wka, flags);
  bias_softmax<<<2, 256, 0, stream>>>(bqa, bka, qwv, kwv);
  prep_w<<<5120, 256, 0, stream>>>(Wq, Wk, Wv, Wqa, Wka, wcat, wqa16, wka16);
  copy_bias<<<12, 256, 0, stream>>>(bq, bk, bv, bcat);
  ln_kernel<<<ROWS, 256, 0, stream>>>(x, gamma, beta, h16);
  // q|k|v = h @ [Wq|Wk|Wv] + b   (M=16384, N=3072, K=1024)
  gemm8<<<dim3(12, 64), 512, 131072, stream>>>(h16, 1024, wcat, bcat, qkv16, 3072, nullptr);
  // logits = q @ Wqa + bqa  (skipped when Wqa == 0)
  gemm8<<<dim3(4, 64), 512, 131072, stream>>>(q16, 3072, wqa16, bqa, logits, 1024, flags);
  softmax_k<<<ROWS, 256, 0, stream>>>(logits, sw, flags);
  // mixed = (cumsum(qw.*q)/scale) .* k
  cs_partial<<<dim3(1, NC, BS), 128, 0, stream>>>(flags, qwv, sw, 1024, q16, 3072, part);
  cs_apply<true><<<dim3(1, NC, BS), 128, 0, stream>>>(flags, qwv, sw, 1024, q16, 3072,
                                                      k16, 3072, part, msum, mixed16, nullptr);
  // logits = mixed @ Wka + bka  (skipped when Wka == 0)
  gemm8<<<dim3(4, 64), 512, 131072, stream>>>(mixed16, 1024, wka16, bka, logits, 1024, flags + 1);
  softmax_k<<<ROWS, 256, 0, stream>>>(logits, sw, flags + 1);
  // out = (cumsum(kw.*mixed)/scale) .* v
  cs_partial2<<<dim3(1, NC, BS), 128, 0, stream>>>(flags + 1, kwv, msum, sw, 1024,
                                                   mixed16, 1024, part);
  cs_apply<false><<<dim3(1, NC, BS), 128, 0, stream>>>(flags + 1, kwv, sw, 1024, mixed16, 1024,
                                                       v16, 3072, part, nullptr, nullptr, out);
}

// Round 8
// 220.934 us; speedup vs baseline: 1.2957x; 1.1993x over previous
//
#include <hip/hip_runtime.h>

typedef _Float16 half_t;
typedef _Float16 f16x8 __attribute__((ext_vector_type(8)));
typedef _Float16 f16x4 __attribute__((ext_vector_type(4)));
typedef float f32x4 __attribute__((ext_vector_type(4)));

#define D_MODEL 1024
#define BS 4
#define SEQ 4096
#define ROWS (BS * SEQ)   // 16384
#define SC 32
#define NC (SEQ / SC)     // 128

#define BARRIER() asm volatile("s_barrier" ::: "memory")
#define WAITV(n)  asm volatile("s_waitcnt vmcnt(" #n ")" ::: "memory")

__device__ __forceinline__ void gld_lds16(const half_t* g, char* l) {
  __builtin_amdgcn_global_load_lds((const __attribute__((address_space(1))) void*)g,
                                   (__attribute__((address_space(3))) void*)l, 16, 0, 0);
}

// ---------------- flags: detect all-zero weight matrices ----------------
__global__ void zero_flags(int* f) {
  if (threadIdx.x < 2) f[threadIdx.x] = 0;
}

__global__ __launch_bounds__(256) void detect_nz(const float* __restrict__ W0,
                                                 const float* __restrict__ W1,
                                                 int* __restrict__ flags) {
  const int which = blockIdx.x >> 8;
  const unsigned* w = (const unsigned*)(which ? W1 : W0);
  const int blk = blockIdx.x & 255;
  unsigned v = 0;
  const size_t base = (size_t)blk * 4096 + threadIdx.x;
#pragma unroll
  for (int i = 0; i < 16; ++i) v |= w[base + i * 256];
#pragma unroll
  for (int off = 32; off > 0; off >>= 1) v |= __shfl_down(v, off, 64);
  __shared__ unsigned sv[4];
  if ((threadIdx.x & 63) == 0) sv[threadIdx.x >> 6] = v;
  __syncthreads();
  if (threadIdx.x == 0) {
    v = sv[0] | sv[1] | sv[2] | sv[3];
    if (v) atomicOr(&flags[which], 1);
  }
}

// ---------------- softmax of (bias/32): one 1024-vector per bias, f32 ----------------
__global__ __launch_bounds__(256) void bias_softmax(const float* __restrict__ bqa,
                                                    const float* __restrict__ bka,
                                                    float* __restrict__ qwv,
                                                    float* __restrict__ kwv) {
  const float* b = blockIdx.x ? bka : bqa;
  float* o = blockIdx.x ? kwv : qwv;
  const int t = threadIdx.x;
  f32x4 v = *(const f32x4*)(b + t * 4);
  float x[4];
#pragma unroll
  for (int i = 0; i < 4; i++) x[i] = v[i] * 0.03125f;
  float mx = fmaxf(fmaxf(x[0], x[1]), fmaxf(x[2], x[3]));
#pragma unroll
  for (int off = 32; off > 0; off >>= 1) mx = fmaxf(mx, __shfl_xor(mx, off, 64));
  __shared__ float sm[4], ssum[4];
  const int wv = t >> 6, ln = t & 63;
  if (ln == 0) sm[wv] = mx;
  __syncthreads();
  mx = fmaxf(fmaxf(sm[0], sm[1]), fmaxf(sm[2], sm[3]));
  float e[4]; float s = 0.f;
#pragma unroll
  for (int i = 0; i < 4; i++) { e[i] = expf(x[i] - mx); s += e[i]; }
#pragma unroll
  for (int off = 32; off > 0; off >>= 1) s += __shfl_xor(s, off, 64);
  if (ln == 0) ssum[wv] = s;
  __syncthreads();
  s = ssum[0] + ssum[1] + ssum[2] + ssum[3];
  const float r = 1.0f / s;
  f32x4 ov;
#pragma unroll
  for (int i = 0; i < 4; i++) ov[i] = e[i] * r;
  *(f32x4*)(o + t * 4) = ov;
}

// ---------------- LayerNorm: fp32 in -> f16 out ----------------
__global__ __launch_bounds__(256) void ln_kernel(const float* __restrict__ x,
                                                 const float* __restrict__ gamma,
                                                 const float* __restrict__ beta,
                                                 half_t* __restrict__ h) {
  const int row = blockIdx.x;
  const int t = threadIdx.x;
  const float* xr = x + (size_t)row * D_MODEL + t * 4;
  f32x4 v = *(const f32x4*)xr;
  float s = v[0] + v[1] + v[2] + v[3];
  float q = v[0]*v[0] + v[1]*v[1] + v[2]*v[2] + v[3]*v[3];
#pragma unroll
  for (int off = 32; off > 0; off >>= 1) {
    s += __shfl_down(s, off, 64);
    q += __shfl_down(q, off, 64);
  }
  __shared__ float rs[4], rq[4];
  const int wv = t >> 6, ln = t & 63;
  if (ln == 0) { rs[wv] = s; rq[wv] = q; }
  __syncthreads();
  s = rs[0] + rs[1] + rs[2] + rs[3];
  q = rq[0] + rq[1] + rq[2] + rq[3];
  const float mu = s * (1.0f / D_MODEL);
  const float var = q * (1.0f / D_MODEL) - mu * mu;
  const float rstd = rsqrtf(var + 1e-5f);
  f32x4 g = *(const f32x4*)(gamma + t * 4);
  f32x4 b = *(const f32x4*)(beta + t * 4);
  f16x4 o;
#pragma unroll
  for (int i = 0; i < 4; i++) o[i] = (half_t)((v[i] - mu) * rstd * g[i] + b[i]);
  *(f16x4*)(h + (size_t)row * D_MODEL + t * 4) = o;
}

// ---------------- weight prepack: fp32 [K][N] -> f16 [N][K] ----------------
__global__ __launch_bounds__(256) void prep_w(const float* __restrict__ Wq,
                                              const float* __restrict__ Wk,
                                              const float* __restrict__ Wv,
                                              const float* __restrict__ Wqa,
                                              const float* __restrict__ Wka,
                                              half_t* __restrict__ wcat,
                                              half_t* __restrict__ wqa,
                                              half_t* __restrict__ wka) {
  const int b = blockIdx.x;
  const int mat = b >> 10;
  const int tile = b & 1023;
  const int tn = (tile & 31) * 32;
  const int tk = (tile >> 5) * 32;
  const float* W = mat == 0 ? Wq : mat == 1 ? Wk : mat == 2 ? Wv : mat == 3 ? Wqa : Wka;
  half_t* dst = mat < 3 ? wcat + (size_t)mat * D_MODEL * D_MODEL : (mat == 3 ? wqa : wka);
  __shared__ float tl[32][33];
  const int tx = threadIdx.x & 31, ty = threadIdx.x >> 5;
#pragma unroll
  for (int i = 0; i < 32; i += 8)
    tl[ty + i][tx] = W[(size_t)(tk + ty + i) * D_MODEL + tn + tx];
  __syncthreads();
#pragma unroll
  for (int i = 0; i < 32; i += 8)
    dst[(size_t)(tn + ty + i) * D_MODEL + tk + tx] = (half_t)tl[tx][ty + i];
}

__global__ __launch_bounds__(256) void copy_bias(const float* __restrict__ bq,
                                                 const float* __restrict__ bk,
                                                 const float* __restrict__ bv,
                                                 float* __restrict__ bcat) {
  const int i = blockIdx.x * 256 + threadIdx.x;
  if (i < 1024) bcat[i] = bq[i];
  else if (i < 2048) bcat[i] = bk[i - 1024];
  else if (i < 3072) bcat[i] = bv[i - 2048];
}

// ---------------- 256x256 8-phase MFMA GEMM (16x16x32), K=1024 fixed ----------------
// R5 version: one barrier per phase (end only); stage slots:
//   P1:Bδ(b) P2:Aα(c) P3:Bγ(c) P4:Aβ(c)+w6 P5:Bδ(c) P6:Aα(d) P7:Bγ(d) P8:Aβ(d)+w6

#define SA2(buf, rb, kt) do { \
  gld_lds16(gA + (size_t)((rb) + wbA + r8) * lda + (size_t)(kt) * 64 + grn * 8, \
            smem + (buf)*65536 + ((rb) + wbA) * 128); \
  gld_lds16(gA + (size_t)((rb) + 128 + wbA + r8) * lda + (size_t)(kt) * 64 + grn * 8, \
            smem + (buf)*65536 + ((rb) + 128 + wbA) * 128); \
} while (0)

#define SB2(buf, gd, kt) do { \
  gld_lds16(gB + (size_t)((gd) + wbB + r8) * 1024 + (size_t)(kt) * 64 + grn * 8, \
            smem + (buf)*65536 + 32768 + ((gd) + wbB) * 128); \
  gld_lds16(gB + (size_t)((gd) + 128 + wbB + r8) * 1024 + (size_t)(kt) * 64 + grn * 8, \
            smem + (buf)*65536 + 32768 + ((gd) + 128 + wbB) * 128); \
} while (0)

#define LOAD_A(buf, base) do { \
  _Pragma("unroll") for (int _fm = 0; _fm < 4; ++_fm) { \
    aF[_fm][0] = *(const f16x8*)(smem + (buf)*65536 + rA + gsw0 + ((base)+_fm)*2048); \
    aF[_fm][1] = *(const f16x8*)(smem + (buf)*65536 + rA + gsw1 + ((base)+_fm)*2048); \
  } \
} while (0)

#define LOAD_B(dst, buf, base) do { \
  _Pragma("unroll") for (int _fn = 0; _fn < 2; ++_fn) { \
    dst[_fn][0] = *(const f16x8*)(smem + (buf)*65536 + 32768 + rB + gsw0 + ((base)+_fn)*2048); \
    dst[_fn][1] = *(const f16x8*)(smem + (buf)*65536 + 32768 + rB + gsw1 + ((base)+_fn)*2048); \
  } \
} while (0)

#define QUAD(BR, MOFF, NOFF) do { \
  __builtin_amdgcn_s_setprio(1); \
  _Pragma("unroll") for (int _fm = 0; _fm < 4; ++_fm) \
  _Pragma("unroll") for (int _fn = 0; _fn < 2; ++_fn) { \
    acc[(MOFF)+_fm][(NOFF)+_fn] = __builtin_amdgcn_mfma_f32_16x16x32_f16(aF[_fm][0], BR[_fn][0], acc[(MOFF)+_fm][(NOFF)+_fn], 0, 0, 0); \
    acc[(MOFF)+_fm][(NOFF)+_fn] = __builtin_amdgcn_mfma_f32_16x16x32_f16(aF[_fm][1], BR[_fn][1], acc[(MOFF)+_fm][(NOFF)+_fn], 0, 0, 0); \
  } \
  __builtin_amdgcn_s_setprio(0); \
} while (0)

__global__ __launch_bounds__(512, 2) void gemm8(const half_t* __restrict__ A, int lda,
                                                const half_t* __restrict__ Bt,
                                                const float* __restrict__ bias,
                                                half_t* __restrict__ C, int ldc,
                                                const int* skip) {
  if (skip && *skip == 0) return;
  extern __shared__ char smem[];
  const int t = threadIdx.x;
  const int ln = t & 63, wid = t >> 6;
  const int wm = wid >> 2, wn = wid & 3;

  const int gx = gridDim.x;
  const int nwg = gx * gridDim.y;
  const int orig = blockIdx.y * gx + blockIdx.x;
  const int swz = (orig & 7) * (nwg >> 3) + (orig >> 3);
  const int bx = swz % gx, by = swz / gx;
  const int n0 = bx * 256, m0 = by * 256;

  const int r8 = (t >> 3) & 7;
  const int grn = (t & 7) ^ r8;
  const int wbA = wid * 8;
  const int wbB = ((wid >> 2) << 6) + (wid & 3) * 8;
  const half_t* gA = A + (size_t)m0 * lda;
  const half_t* gB = Bt + (size_t)n0 * 1024;

  const int rA = (wm * 128 + (ln & 15)) * 128;
  const int rB = (wn * 64 + (ln & 15)) * 128;
  const int gsw0 = (((ln >> 4)) ^ (ln & 7)) << 4;
  const int gsw1 = ((4 | (ln >> 4)) ^ (ln & 7)) << 4;

  f32x4 acc[8][4] = {};
  f16x8 aF[4][2], bL[2][2], bH[2][2];

  // prologue: tile0 complete, tile1 Aα,Bγ,Aβ (Bδ(1) staged at i=0 P1)
  SA2(0, 0, 0); SB2(0, 0, 0); SA2(0, 64, 0); SB2(0, 32, 0);
  SA2(1, 0, 1); SB2(1, 0, 1); SA2(1, 64, 1);
  WAITV(6); BARRIER();

#pragma unroll 1
  for (int i = 0; i < 8; ++i) {
    const int kb = 2 * i + 1;
    const int kc = 2 * i + 2;
    const int kd = 2 * i + 3;
    const bool f = (i < 7);
    // ---- P1: read aLow+bL+bH (buf0); stage Bδ(b); Q0
    LOAD_A(0, 0); LOAD_B(bL, 0, 0); LOAD_B(bH, 0, 2);
    SB2(1, 32, kb);
    QUAD(bL, 0, 0); BARRIER();
    // ---- P2: stage Aα(c); Q1 (operands already in regs)
    if (f) SA2(0, 0, kc);
    QUAD(bH, 0, 2); BARRIER();
    // ---- P3: read aHigh(buf0); stage Bγ(c); Q2
    LOAD_A(0, 4);
    if (f) SB2(0, 0, kc);
    QUAD(bH, 4, 2); BARRIER();
    // ---- P4: stage Aβ(c); counted wait; Q3 (ready)
    if (f) { SA2(0, 64, kc); WAITV(6); } else WAITV(0);
    QUAD(bL, 4, 0); BARRIER();
    // ---- P5: reads (buf1); stage Bδ(c); Q0
    LOAD_A(1, 0); LOAD_B(bL, 1, 0); LOAD_B(bH, 1, 2);
    if (f) SB2(0, 32, kc);
    QUAD(bL, 0, 0); BARRIER();
    // ---- P6: stage Aα(d); Q1
    if (f) SA2(1, 0, kd);
    QUAD(bH, 0, 2); BARRIER();
    // ---- P7: read aHigh(buf1); stage Bγ(d); Q2
    LOAD_A(1, 4);
    if (f) SB2(1, 0, kd);
    QUAD(bH, 4, 2); BARRIER();
    // ---- P8: stage Aβ(d); counted wait; Q3
    if (f) { SA2(1, 64, kd); WAITV(6); }
    QUAD(bL, 4, 0); BARRIER();
  }

  const int r0 = m0 + wm * 128 + ((ln >> 4) << 2);
  const int c0 = n0 + wn * 64 + (ln & 15);
  float bb[4];
#pragma unroll
  for (int fn = 0; fn < 4; ++fn) bb[fn] = bias[c0 + fn * 16];
#pragma unroll
  for (int fm = 0; fm < 8; ++fm)
#pragma unroll
    for (int fn = 0; fn < 4; ++fn) {
      const int col = c0 + fn * 16;
      const int row = r0 + fm * 16;
#pragma unroll
      for (int r = 0; r < 4; ++r)
        C[(size_t)(row + r) * ldc + col] = (half_t)(acc[fm][fn][r] + bb[fn]);
    }
}

// ---------------- row softmax over D=1024, logits scaled 1/32 ----------------
__global__ __launch_bounds__(256) void softmax_k(const half_t* __restrict__ L,
                                                 half_t* __restrict__ O,
                                                 const int* skip) {
  if (skip && *skip == 0) return;
  const size_t row = blockIdx.x;
  const int t = threadIdx.x;
  f16x4 v = *(const f16x4*)(L + row * D_MODEL + t * 4);
  float x[4];
#pragma unroll
  for (int i = 0; i < 4; i++) x[i] = (float)v[i] * 0.03125f;
  float mx = fmaxf(fmaxf(x[0], x[1]), fmaxf(x[2], x[3]));
#pragma unroll
  for (int off = 32; off > 0; off >>= 1) mx = fmaxf(mx, __shfl_xor(mx, off, 64));
  __shared__ float sm[4], ssum[4];
  const int wv = t >> 6, ln = t & 63;
  if (ln == 0) sm[wv] = mx;
  __syncthreads();
  mx = fmaxf(fmaxf(sm[0], sm[1]), fmaxf(sm[2], sm[3]));
  float e[4]; float s = 0.f;
#pragma unroll
  for (int i = 0; i < 4; i++) { e[i] = expf(x[i] - mx); s += e[i]; }
#pragma unroll
  for (int off = 32; off > 0; off >>= 1) s += __shfl_xor(s, off, 64);
  if (ln == 0) ssum[wv] = s;
  __syncthreads();
  s = ssum[0] + ssum[1] + ssum[2] + ssum[3];
  const float r = 1.0f / s;
  f16x4 o;
#pragma unroll
  for (int i = 0; i < 4; i++) o[i] = (half_t)(e[i] * r);
  *(f16x4*)(O + row * D_MODEL + t * 4) = o;
}

// ---------------- cumsum pass 1: per-chunk sums, 4 d-elems/thread ----------------
__global__ __launch_bounds__(256) void cs_partial(const int* __restrict__ nz,
                                                  const float* __restrict__ wv,
                                                  const half_t* __restrict__ A, int ldA,
                                                  const half_t* __restrict__ B, int ldB,
                                                  float* __restrict__ part) {
  const int d = threadIdx.x * 4;
  const int c = blockIdx.y;
  const int bb = blockIdx.z;
  const size_t s0 = (size_t)bb * SEQ + (size_t)c * SC;
  const half_t* pa = A + s0 * ldA + d;
  const half_t* pb = B + s0 * ldB + d;
  float acc[4] = {};
  if (*nz == 0) {
    f32x4 w = *(const f32x4*)&wv[d];
#pragma unroll 4
    for (int s = 0; s < SC; s++) {
      f16x4 b = *(const f16x4*)&pb[(size_t)s * ldB];
#pragma unroll
      for (int j = 0; j < 4; j++) acc[j] += w[j] * (float)b[j];
    }
  } else {
#pragma unroll 4
    for (int s = 0; s < SC; s++) {
      f16x4 a = *(const f16x4*)&pa[(size_t)s * ldA];
      f16x4 b = *(const f16x4*)&pb[(size_t)s * ldB];
#pragma unroll
      for (int j = 0; j < 4; j++) acc[j] += (float)a[j] * (float)b[j];
    }
  }
  *(f32x4*)&part[((size_t)bb * NC + c) * D_MODEL + d] = *(f32x4*)acc;
}

// ---------------- cumsum pass 1 for stage 2 (shortcut uses msum) ----------------
__global__ __launch_bounds__(256) void cs_partial2(const int* __restrict__ nz,
                                                   const float* __restrict__ wv,
                                                   const float* __restrict__ msum,
                                                   const half_t* __restrict__ A, int ldA,
                                                   const half_t* __restrict__ B, int ldB,
                                                   float* __restrict__ part) {
  const int d = threadIdx.x * 4;
  const int c = blockIdx.y;
  const int bb = blockIdx.z;
  const size_t idx = ((size_t)bb * NC + c) * D_MODEL + d;
  if (*nz == 0) {
    f32x4 w = *(const f32x4*)&wv[d];
    f32x4 m = *(const f32x4*)&msum[idx];
#pragma unroll
    for (int j = 0; j < 4; j++) m[j] *= w[j];
    *(f32x4*)&part[idx] = m;
    return;
  }
  const size_t s0 = (size_t)bb * SEQ + (size_t)c * SC;
  const half_t* pa = A + s0 * ldA + d;
  const half_t* pb = B + s0 * ldB + d;
  float acc[4] = {};
#pragma unroll 4
  for (int s = 0; s < SC; s++) {
    f16x4 a = *(const f16x4*)&pa[(size_t)s * ldA];
    f16x4 b = *(const f16x4*)&pb[(size_t)s * ldB];
#pragma unroll
    for (int j = 0; j < 4; j++) acc[j] += (float)a[j] * (float)b[j];
  }
  *(f32x4*)&part[idx] = *(f32x4*)acc;
}

// ---------------- exclusive scan of part over chunks (in place) ----------------
__global__ __launch_bounds__(256) void cs_scan(float* __restrict__ part) {
  const int d = blockIdx.x * 256 + threadIdx.x;
  const int bb = blockIdx.y;
  float* p = part + (size_t)bb * NC * D_MODEL + d;
  float acc = 0.f;
#pragma unroll 8
  for (int c = 0; c < NC; c++) {
    const float v = p[(size_t)c * D_MODEL];
    p[(size_t)c * D_MODEL] = acc;
    acc += v;
  }
}

// ---------------- cumsum pass 2: prefix is a single read; 4 d-elems/thread ----------------
template <bool HALF_OUT>
__global__ __launch_bounds__(256) void cs_apply(const int* __restrict__ nz,
                                                const float* __restrict__ wv,
                                                const half_t* __restrict__ A, int ldA,
                                                const half_t* __restrict__ B, int ldB,
                                                const half_t* __restrict__ Cm, int ldC,
                                                const float* __restrict__ part,
                                                float* __restrict__ msum,
                                                half_t* __restrict__ OH,
                                                float* __restrict__ OF) {
  const int d = threadIdx.x * 4;
  const int c = blockIdx.y;
  const int bb = blockIdx.z;
  const size_t idx = ((size_t)bb * NC + c) * D_MODEL + d;
  f32x4 pr = *(const f32x4*)&part[idx];
  float acc[4] = {pr[0], pr[1], pr[2], pr[3]};
  const size_t s0 = (size_t)bb * SEQ + (size_t)c * SC;
  float ms[4] = {};
  if (*nz == 0) {
    f32x4 w = *(const f32x4*)&wv[d];
#pragma unroll 4
    for (int s = 0; s < SC; s++) {
      const size_t sg = s0 + s;
      f16x4 b = *(const f16x4*)&B[sg * ldB + d];
      f16x4 cm = *(const f16x4*)&Cm[sg * ldC + d];
      const float rinv = 1.0f / (float)(c * SC + s + 1);
      float m[4];
#pragma unroll
      for (int j = 0; j < 4; j++) {
        acc[j] += w[j] * (float)b[j];
        m[j] = acc[j] * rinv * (float)cm[j];
        ms[j] += m[j];
      }
      if (HALF_OUT) {
        f16x4 o;
#pragma unroll
        for (int j = 0; j < 4; j++) o[j] = (half_t)m[j];
        *(f16x4*)&OH[sg * D_MODEL + d] = o;
      } else {
        *(f32x4*)&OF[sg * D_MODEL + d] = *(f32x4*)m;
      }
    }
  } else {
#pragma unroll 4
    for (int s = 0; s < SC; s++) {
      const size_t sg = s0 + s;
      f16x4 a = *(const f16x4*)&A[sg * ldA + d];
      f16x4 b = *(const f16x4*)&B[sg * ldB + d];
      f16x4 cm = *(const f16x4*)&Cm[sg * ldC + d];
      const float rinv = 1.0f / (float)(c * SC + s + 1);
      float m[4];
#pragma unroll
      for (int j = 0; j < 4; j++) {
        acc[j] += (float)a[j] * (float)b[j];
        m[j] = acc[j] * rinv * (float)cm[j];
        ms[j] += m[j];
      }
      if (HALF_OUT) {
        f16x4 o;
#pragma unroll
        for (int j = 0; j < 4; j++) o[j] = (half_t)m[j];
        *(f16x4*)&OH[sg * D_MODEL + d] = o;
      } else {
        *(f32x4*)&OF[sg * D_MODEL + d] = *(f32x4*)m;
      }
    }
  }
  if (msum) *(f32x4*)&msum[idx] = *(f32x4*)ms;
}

extern "C" void kernel_launch(void* const* d_in, const int* in_sizes, int n_in,
                              void* d_out, int out_size, void* d_ws, size_t ws_size,
                              hipStream_t stream) {
  const float* x     = (const float*)d_in[0];
  const float* Wq    = (const float*)d_in[2];
  const float* bq    = (const float*)d_in[3];
  const float* Wqa   = (const float*)d_in[4];
  const float* bqa   = (const float*)d_in[5];
  const float* Wk    = (const float*)d_in[6];
  const float* bk    = (const float*)d_in[7];
  const float* Wka   = (const float*)d_in[8];
  const float* bka   = (const float*)d_in[9];
  const float* Wv    = (const float*)d_in[10];
  const float* bv    = (const float*)d_in[11];
  const float* gamma = (const float*)d_in[12];
  const float* beta  = (const float*)d_in[13];
  float* out = (float*)d_out;

  char* ws = (char*)d_ws;
  const size_t MB = 1024 * 1024;
  half_t* h16    = (half_t*)(ws + 0);         // 32MB: h, later reused as mixed16
  half_t* qkv16  = (half_t*)(ws + 32 * MB);   // 96MB: [16384][3072] q|k|v
  half_t* logits = (half_t*)(ws + 128 * MB);  // 32MB
  half_t* wcat   = (half_t*)(ws + 160 * MB);  // 6MB (dead after gemm1)
  half_t* wqa16  = (half_t*)(ws + 166 * MB);  // 2MB
  half_t* wka16  = (half_t*)(ws + 168 * MB);  // 2MB
  float*  bcat   = (float*)(ws + 170 * MB);   // 12KB
  // part/msum live in the dead-wcat region (used only after gemm1)
  float*  part   = (float*)(ws + 160 * MB);          // 2MB [BS][NC=128][1024] f32
  float*  msum   = (float*)(ws + 162 * MB);          // 2MB
  float*  qwv    = (float*)(ws + 170 * MB + 64 * 1024);  // 4KB
  float*  kwv    = (float*)(ws + 170 * MB + 68 * 1024);  // 4KB
  int*    flags  = (int*)(ws + 170 * MB + 72 * 1024);    // 8B

  half_t* q16 = qkv16;            // lda 3072
  half_t* k16 = qkv16 + 1024;
  half_t* v16 = qkv16 + 2048;
  half_t* mixed16 = h16;
  half_t* sw = logits;

  hipFuncSetAttribute((const void*)gemm8, hipFuncAttributeMaxDynamicSharedMemorySize, 131072);

  zero_flags<<<1, 64, 0, stream>>>(flags);
  detect_nz<<<512, 256, 0, stream>>>(Wqa, Wka, flags);
  bias_softmax<<<2, 256, 0, stream>>>(bqa, bka, qwv, kwv);
  prep_w<<<5120, 256, 0, stream>>>(Wq, Wk, Wv, Wqa, Wka, wcat, wqa16, wka16);
  copy_bias<<<12, 256, 0, stream>>>(bq, bk, bv, bcat);
  ln_kernel<<<ROWS, 256, 0, stream>>>(x, gamma, beta, h16);
  // q|k|v = h @ [Wq|Wk|Wv] + b   (M=16384, N=3072, K=1024)
  gemm8<<<dim3(12, 64), 512, 131072, stream>>>(h16, 1024, wcat, bcat, qkv16, 3072, nullptr);
  // logits = q @ Wqa + bqa  (skipped when Wqa == 0)
  gemm8<<<dim3(4, 64), 512, 131072, stream>>>(q16, 3072, wqa16, bqa, logits, 1024, flags);
  softmax_k<<<ROWS, 256, 0, stream>>>(logits, sw, flags);
  // mixed = (cumsum(qw.*q)/scale) .* k
  cs_partial<<<dim3(1, NC, BS), 256, 0, stream>>>(flags, qwv, sw, 1024, q16, 3072, part);
  cs_scan<<<dim3(4, BS), 256, 0, stream>>>(part);
  cs_apply<true><<<dim3(1, NC, BS), 256, 0, stream>>>(flags, qwv, sw, 1024, q16, 3072,
                                                      k16, 3072, part, msum, mixed16, nullptr);
  // logits = mixed @ Wka + bka  (skipped when Wka == 0)
  gemm8<<<dim3(4, 64), 512, 131072, stream>>>(mixed16, 1024, wka16, bka, logits, 1024, flags + 1);
  softmax_k<<<ROWS, 256, 0, stream>>>(logits, sw, flags + 1);
  // out = (cumsum(kw.*mixed)/scale) .* v
  cs_partial2<<<dim3(1, NC, BS), 256, 0, stream>>>(flags + 1, kwv, msum, sw, 1024,
                                                   mixed16, 1024, part);
  cs_scan<<<dim3(4, BS), 256, 0, stream>>>(part);
  cs_apply<false><<<dim3(1, NC, BS), 256, 0, stream>>>(flags + 1, kwv, sw, 1024, mixed16, 1024,
                                                       v16, 3072, part, nullptr, nullptr, out);
}

// Round 9
// 199.670 us; speedup vs baseline: 1.4337x; 1.1065x over previous
//
#include <hip/hip_runtime.h>

typedef _Float16 half_t;
typedef _Float16 f16x8 __attribute__((ext_vector_type(8)));
typedef _Float16 f16x4 __attribute__((ext_vector_type(4)));
typedef float f32x4 __attribute__((ext_vector_type(4)));

#define D_MODEL 1024
#define BS 4
#define SEQ 4096
#define ROWS (BS * SEQ)   // 16384
#define SC 32
#define NC (SEQ / SC)     // 128

#define BARRIER() asm volatile("s_barrier" ::: "memory")
#define WAITV(n)  asm volatile("s_waitcnt vmcnt(" #n ")" ::: "memory")

__device__ __forceinline__ void gld_lds16(const half_t* g, char* l) {
  __builtin_amdgcn_global_load_lds((const __attribute__((address_space(1))) void*)g,
                                   (__attribute__((address_space(3))) void*)l, 16, 0, 0);
}

// ================= setup1: ln + prep_w + detect_nz + copy_bias (fused) =================
__global__ __launch_bounds__(256) void setup1(const float* __restrict__ x,
                                              const float* __restrict__ gamma,
                                              const float* __restrict__ beta,
                                              half_t* __restrict__ h,
                                              const float* __restrict__ Wq,
                                              const float* __restrict__ Wk,
                                              const float* __restrict__ Wv,
                                              const float* __restrict__ Wqa,
                                              const float* __restrict__ Wka,
                                              half_t* __restrict__ wcat,
                                              half_t* __restrict__ wqa,
                                              half_t* __restrict__ wka,
                                              const float* __restrict__ bq,
                                              const float* __restrict__ bk,
                                              const float* __restrict__ bv,
                                              float* __restrict__ bcat,
                                              unsigned* __restrict__ nzpart) {
  __shared__ float sh[33 * 32];
  const int b = blockIdx.x;
  const int t = threadIdx.x;
  if (b < 16384) {
    // ---- layernorm row b ----
    const float* xr = x + (size_t)b * D_MODEL + t * 4;
    f32x4 v = *(const f32x4*)xr;
    float s = v[0] + v[1] + v[2] + v[3];
    float q = v[0]*v[0] + v[1]*v[1] + v[2]*v[2] + v[3]*v[3];
#pragma unroll
    for (int off = 32; off > 0; off >>= 1) {
      s += __shfl_down(s, off, 64);
      q += __shfl_down(q, off, 64);
    }
    const int wv = t >> 6, ln = t & 63;
    if (ln == 0) { sh[wv] = s; sh[4 + wv] = q; }
    __syncthreads();
    s = sh[0] + sh[1] + sh[2] + sh[3];
    q = sh[4] + sh[5] + sh[6] + sh[7];
    const float mu = s * (1.0f / D_MODEL);
    const float var = q * (1.0f / D_MODEL) - mu * mu;
    const float rstd = rsqrtf(var + 1e-5f);
    f32x4 g = *(const f32x4*)(gamma + t * 4);
    f32x4 bb = *(const f32x4*)(beta + t * 4);
    f16x4 o;
#pragma unroll
    for (int i = 0; i < 4; i++) o[i] = (half_t)((v[i] - mu) * rstd * g[i] + bb[i]);
    *(f16x4*)(h + (size_t)b * D_MODEL + t * 4) = o;
  } else if (b < 21504) {
    // ---- weight prepack tile ----
    const int bi = b - 16384;
    const int mat = bi >> 10;
    const int tile = bi & 1023;
    const int tn = (tile & 31) * 32;
    const int tk = (tile >> 5) * 32;
    const float* W = mat == 0 ? Wq : mat == 1 ? Wk : mat == 2 ? Wv : mat == 3 ? Wqa : Wka;
    half_t* dst = mat < 3 ? wcat + (size_t)mat * D_MODEL * D_MODEL : (mat == 3 ? wqa : wka);
    float (*tl)[33] = (float(*)[33])sh;
    const int tx = t & 31, ty = t >> 5;
#pragma unroll
    for (int i = 0; i < 32; i += 8)
      tl[ty + i][tx] = W[(size_t)(tk + ty + i) * D_MODEL + tn + tx];
    __syncthreads();
#pragma unroll
    for (int i = 0; i < 32; i += 8)
      dst[(size_t)(tn + ty + i) * D_MODEL + tk + tx] = (half_t)tl[tx][ty + i];
  } else if (b < 22016) {
    // ---- detect nonzero: per-block OR -> nzpart ----
    const int bi = b - 21504;
    const int which = bi >> 8;
    const unsigned* w = (const unsigned*)(which ? Wka : Wqa);
    const int blk = bi & 255;
    unsigned v = 0;
    const size_t base = (size_t)blk * 4096 + t;
#pragma unroll
    for (int i = 0; i < 16; ++i) v |= w[base + i * 256];
#pragma unroll
    for (int off = 32; off > 0; off >>= 1) v |= __shfl_down(v, off, 64);
    unsigned* sv = (unsigned*)sh;
    if ((t & 63) == 0) sv[t >> 6] = v;
    __syncthreads();
    if (t == 0) nzpart[bi] = sv[0] | sv[1] | sv[2] | sv[3];
  } else {
    // ---- copy_bias ----
    const int i = (b - 22016) * 256 + t;
    if (i < 1024) bcat[i] = bq[i];
    else if (i < 2048) bcat[i] = bk[i - 1024];
    else if (i < 3072) bcat[i] = bv[i - 2048];
  }
}

// ================= setup2: flag reduce + bias softmax (2 blocks) =================
__global__ __launch_bounds__(256) void setup2(const unsigned* __restrict__ nzpart,
                                              int* __restrict__ flags,
                                              const float* __restrict__ bqa,
                                              const float* __restrict__ bka,
                                              float* __restrict__ qwv,
                                              float* __restrict__ kwv) {
  const int b = blockIdx.x;
  const int t = threadIdx.x;
  __shared__ float sm[4], ssum[4];
  __shared__ unsigned su[4];
  // flag reduce
  unsigned u = nzpart[b * 256 + t];
#pragma unroll
  for (int off = 32; off > 0; off >>= 1) u |= __shfl_down(u, off, 64);
  const int wv = t >> 6, ln = t & 63;
  if (ln == 0) su[wv] = u;
  __syncthreads();
  if (t == 0) flags[b] = (su[0] | su[1] | su[2] | su[3]) ? 1 : 0;
  // bias softmax
  const float* bb = b ? bka : bqa;
  float* o = b ? kwv : qwv;
  f32x4 v = *(const f32x4*)(bb + t * 4);
  float xv[4];
#pragma unroll
  for (int i = 0; i < 4; i++) xv[i] = v[i] * 0.03125f;
  float mx = fmaxf(fmaxf(xv[0], xv[1]), fmaxf(xv[2], xv[3]));
#pragma unroll
  for (int off = 32; off > 0; off >>= 1) mx = fmaxf(mx, __shfl_xor(mx, off, 64));
  if (ln == 0) sm[wv] = mx;
  __syncthreads();
  mx = fmaxf(fmaxf(sm[0], sm[1]), fmaxf(sm[2], sm[3]));
  float e[4]; float s = 0.f;
#pragma unroll
  for (int i = 0; i < 4; i++) { e[i] = expf(xv[i] - mx); s += e[i]; }
#pragma unroll
  for (int off = 32; off > 0; off >>= 1) s += __shfl_xor(s, off, 64);
  if (ln == 0) ssum[wv] = s;
  __syncthreads();
  s = ssum[0] + ssum[1] + ssum[2] + ssum[3];
  const float r = 1.0f / s;
  f32x4 ov;
#pragma unroll
  for (int i = 0; i < 4; i++) ov[i] = e[i] * r;
  *(f32x4*)(o + t * 4) = ov;
}

// ================= 256x256 8-phase MFMA GEMM (16x16x32), K=1024 =================
// R5 schedule. If qp != null, blocks with n0 < 1024 also emit per-chunk (32-row)
// column sums of C (incl. bias) into qp[bb][chunk][col] — one writer per entry.

#define SA2(buf, rb, kt) do { \
  gld_lds16(gA + (size_t)((rb) + wbA + r8) * lda + (size_t)(kt) * 64 + grn * 8, \
            smem + (buf)*65536 + ((rb) + wbA) * 128); \
  gld_lds16(gA + (size_t)((rb) + 128 + wbA + r8) * lda + (size_t)(kt) * 64 + grn * 8, \
            smem + (buf)*65536 + ((rb) + 128 + wbA) * 128); \
} while (0)

#define SB2(buf, gd, kt) do { \
  gld_lds16(gB + (size_t)((gd) + wbB + r8) * 1024 + (size_t)(kt) * 64 + grn * 8, \
            smem + (buf)*65536 + 32768 + ((gd) + wbB) * 128); \
  gld_lds16(gB + (size_t)((gd) + 128 + wbB + r8) * 1024 + (size_t)(kt) * 64 + grn * 8, \
            smem + (buf)*65536 + 32768 + ((gd) + 128 + wbB) * 128); \
} while (0)

#define LOAD_A(buf, base) do { \
  _Pragma("unroll") for (int _fm = 0; _fm < 4; ++_fm) { \
    aF[_fm][0] = *(const f16x8*)(smem + (buf)*65536 + rA + gsw0 + ((base)+_fm)*2048); \
    aF[_fm][1] = *(const f16x8*)(smem + (buf)*65536 + rA + gsw1 + ((base)+_fm)*2048); \
  } \
} while (0)

#define LOAD_B(dst, buf, base) do { \
  _Pragma("unroll") for (int _fn = 0; _fn < 2; ++_fn) { \
    dst[_fn][0] = *(const f16x8*)(smem + (buf)*65536 + 32768 + rB + gsw0 + ((base)+_fn)*2048); \
    dst[_fn][1] = *(const f16x8*)(smem + (buf)*65536 + 32768 + rB + gsw1 + ((base)+_fn)*2048); \
  } \
} while (0)

#define QUAD(BR, MOFF, NOFF) do { \
  __builtin_amdgcn_s_setprio(1); \
  _Pragma("unroll") for (int _fm = 0; _fm < 4; ++_fm) \
  _Pragma("unroll") for (int _fn = 0; _fn < 2; ++_fn) { \
    acc[(MOFF)+_fm][(NOFF)+_fn] = __builtin_amdgcn_mfma_f32_16x16x32_f16(aF[_fm][0], BR[_fn][0], acc[(MOFF)+_fm][(NOFF)+_fn], 0, 0, 0); \
    acc[(MOFF)+_fm][(NOFF)+_fn] = __builtin_amdgcn_mfma_f32_16x16x32_f16(aF[_fm][1], BR[_fn][1], acc[(MOFF)+_fm][(NOFF)+_fn], 0, 0, 0); \
  } \
  __builtin_amdgcn_s_setprio(0); \
} while (0)

__global__ __launch_bounds__(512, 2) void gemm8(const half_t* __restrict__ A, int lda,
                                                const half_t* __restrict__ Bt,
                                                const float* __restrict__ bias,
                                                half_t* __restrict__ C, int ldc,
                                                const int* skip,
                                                float* __restrict__ qp) {
  if (skip && *skip == 0) return;
  extern __shared__ char smem[];
  const int t = threadIdx.x;
  const int ln = t & 63, wid = t >> 6;
  const int wm = wid >> 2, wn = wid & 3;

  const int gx = gridDim.x;
  const int nwg = gx * gridDim.y;
  const int orig = blockIdx.y * gx + blockIdx.x;
  const int swz = (orig & 7) * (nwg >> 3) + (orig >> 3);
  const int bx = swz % gx, by = swz / gx;
  const int n0 = bx * 256, m0 = by * 256;

  const int r8 = (t >> 3) & 7;
  const int grn = (t & 7) ^ r8;
  const int wbA = wid * 8;
  const int wbB = ((wid >> 2) << 6) + (wid & 3) * 8;
  const half_t* gA = A + (size_t)m0 * lda;
  const half_t* gB = Bt + (size_t)n0 * 1024;

  const int rA = (wm * 128 + (ln & 15)) * 128;
  const int rB = (wn * 64 + (ln & 15)) * 128;
  const int gsw0 = (((ln >> 4)) ^ (ln & 7)) << 4;
  const int gsw1 = ((4 | (ln >> 4)) ^ (ln & 7)) << 4;

  f32x4 acc[8][4] = {};
  f16x8 aF[4][2], bL[2][2], bH[2][2];

  SA2(0, 0, 0); SB2(0, 0, 0); SA2(0, 64, 0); SB2(0, 32, 0);
  SA2(1, 0, 1); SB2(1, 0, 1); SA2(1, 64, 1);
  WAITV(6); BARRIER();

#pragma unroll 1
  for (int i = 0; i < 8; ++i) {
    const int kb = 2 * i + 1;
    const int kc = 2 * i + 2;
    const int kd = 2 * i + 3;
    const bool f = (i < 7);
    LOAD_A(0, 0); LOAD_B(bL, 0, 0); LOAD_B(bH, 0, 2);
    SB2(1, 32, kb);
    QUAD(bL, 0, 0); BARRIER();
    if (f) SA2(0, 0, kc);
    QUAD(bH, 0, 2); BARRIER();
    LOAD_A(0, 4);
    if (f) SB2(0, 0, kc);
    QUAD(bH, 4, 2); BARRIER();
    if (f) { SA2(0, 64, kc); WAITV(6); } else WAITV(0);
    QUAD(bL, 4, 0); BARRIER();
    LOAD_A(1, 0); LOAD_B(bL, 1, 0); LOAD_B(bH, 1, 2);
    if (f) SB2(0, 32, kc);
    QUAD(bL, 0, 0); BARRIER();
    if (f) SA2(1, 0, kd);
    QUAD(bH, 0, 2); BARRIER();
    LOAD_A(1, 4);
    if (f) SB2(1, 0, kd);
    QUAD(bH, 4, 2); BARRIER();
    if (f) { SA2(1, 64, kd); WAITV(6); }
    QUAD(bL, 4, 0); BARRIER();
  }

  const int r0 = m0 + wm * 128 + ((ln >> 4) << 2);
  const int c0 = n0 + wn * 64 + (ln & 15);
  float bv4[4];
#pragma unroll
  for (int fn = 0; fn < 4; ++fn) bv4[fn] = bias[c0 + fn * 16];
#pragma unroll
  for (int fm = 0; fm < 8; ++fm)
#pragma unroll
    for (int fn = 0; fn < 4; ++fn) {
      const int col = c0 + fn * 16;
      const int row = r0 + fm * 16;
#pragma unroll
      for (int r = 0; r < 4; ++r)
        C[(size_t)(row + r) * ldc + col] = (half_t)(acc[fm][fn][r] + bv4[fn]);
    }

  // ---- emit per-chunk (32-row) column sums of q (+bias), f32 exact ----
  if (qp && n0 < 1024) {
    const int bb = m0 >> 12;                       // batch
    const int cb = ((m0 & 4095) >> 5) + wm * 4;    // chunk base for this wave
#pragma unroll
    for (int fn = 0; fn < 4; ++fn) {
#pragma unroll
      for (int j = 0; j < 4; ++j) {
        float s8 = bv4[fn] * 8.0f;
#pragma unroll
        for (int r = 0; r < 4; ++r) s8 += acc[2 * j][fn][r] + acc[2 * j + 1][fn][r];
        s8 += __shfl_xor(s8, 16, 64);
        s8 += __shfl_xor(s8, 32, 64);
        if (ln < 16)
          qp[((size_t)bb * NC + cb + j) * D_MODEL + c0 + fn * 16] = s8;
      }
    }
  }
}

// ================= row softmax (8 rows/block), logits scaled 1/32 =================
__global__ __launch_bounds__(256) void softmax_k(const half_t* __restrict__ L,
                                                 half_t* __restrict__ O,
                                                 const int* skip) {
  if (*skip == 0) return;
  const int t = threadIdx.x;
  const int wv = t >> 6, ln = t & 63;
  __shared__ float sm[4], ssum[4];
#pragma unroll 1
  for (int i = 0; i < 8; ++i) {
    const size_t row = (size_t)blockIdx.x * 8 + i;
    f16x4 v = *(const f16x4*)(L + row * D_MODEL + t * 4);
    float x[4];
#pragma unroll
    for (int k = 0; k < 4; k++) x[k] = (float)v[k] * 0.03125f;
    float mx = fmaxf(fmaxf(x[0], x[1]), fmaxf(x[2], x[3]));
#pragma unroll
    for (int off = 32; off > 0; off >>= 1) mx = fmaxf(mx, __shfl_xor(mx, off, 64));
    if (ln == 0) sm[wv] = mx;
    __syncthreads();
    mx = fmaxf(fmaxf(sm[0], sm[1]), fmaxf(sm[2], sm[3]));
    float e[4]; float s = 0.f;
#pragma unroll
    for (int k = 0; k < 4; k++) { e[k] = expf(x[k] - mx); s += e[k]; }
#pragma unroll
    for (int off = 32; off > 0; off >>= 1) s += __shfl_xor(s, off, 64);
    if (ln == 0) ssum[wv] = s;
    __syncthreads();
    s = ssum[0] + ssum[1] + ssum[2] + ssum[3];
    const float r = 1.0f / s;
    f16x4 o;
#pragma unroll
    for (int k = 0; k < 4; k++) o[k] = (half_t)(e[k] * r);
    *(f16x4*)(O + row * D_MODEL + t * 4) = o;
    __syncthreads();
  }
}

// ================= cumsum pass 1 (nz path only) =================
__global__ __launch_bounds__(256) void cs_partial(const int* __restrict__ nz,
                                                  const half_t* __restrict__ A, int ldA,
                                                  const half_t* __restrict__ B, int ldB,
                                                  float* __restrict__ part) {
  if (*nz == 0) return;  // fast path: gemm1 already emitted chunk sums
  const int d = threadIdx.x * 4;
  const int c = blockIdx.y;
  const int bb = blockIdx.z;
  const size_t s0 = (size_t)bb * SEQ + (size_t)c * SC;
  const half_t* pa = A + s0 * ldA + d;
  const half_t* pb = B + s0 * ldB + d;
  float acc[4] = {};
#pragma unroll 4
  for (int s = 0; s < SC; s++) {
    f16x4 a = *(const f16x4*)&pa[(size_t)s * ldA];
    f16x4 b = *(const f16x4*)&pb[(size_t)s * ldB];
#pragma unroll
    for (int j = 0; j < 4; j++) acc[j] += (float)a[j] * (float)b[j];
  }
  *(f32x4*)&part[((size_t)bb * NC + c) * D_MODEL + d] = *(f32x4*)acc;
}

// ================= exclusive scan over chunks (flag-selected buffer) =================
__global__ __launch_bounds__(256) void cs_scan(const int* __restrict__ nz,
                                               float* __restrict__ pz,
                                               float* __restrict__ pn) {
  float* part = (*nz == 0) ? pz : pn;
  const int d = blockIdx.x * 256 + threadIdx.x;
  const int bb = blockIdx.y;
  float* p = part + (size_t)bb * NC * D_MODEL + d;
  float acc = 0.f;
#pragma unroll 8
  for (int c = 0; c < NC; c++) {
    const float v = p[(size_t)c * D_MODEL];
    p[(size_t)c * D_MODEL] = acc;
    acc += v;
  }
}

// ================= cumsum pass 2 =================
// zero path: acc = prefix(plain sums); m = w * acc * rinv * Cm
// nz path:   acc = prefix(weighted sums); acc += A*B; m = acc * rinv * Cm
template <bool HALF_OUT>
__global__ __launch_bounds__(256) void cs_apply(const int* __restrict__ nz,
                                                const float* __restrict__ wv,
                                                const half_t* __restrict__ A, int ldA,
                                                const half_t* __restrict__ B, int ldB,
                                                const half_t* __restrict__ Cm, int ldC,
                                                const float* __restrict__ pz,
                                                const float* __restrict__ pn,
                                                float* __restrict__ msum,
                                                half_t* __restrict__ OH,
                                                float* __restrict__ OF) {
  const int d = threadIdx.x * 4;
  const int c = blockIdx.y;
  const int bb = blockIdx.z;
  const size_t idx = ((size_t)bb * NC + c) * D_MODEL + d;
  const int nzv = *nz;
  f32x4 pr = *(const f32x4*)((nzv == 0 ? pz : pn) + idx);
  float acc[4] = {pr[0], pr[1], pr[2], pr[3]};
  const size_t s0 = (size_t)bb * SEQ + (size_t)c * SC;
  float ms[4] = {};
  if (nzv == 0) {
    f32x4 w = *(const f32x4*)&wv[d];
#pragma unroll 4
    for (int s = 0; s < SC; s++) {
      const size_t sg = s0 + s;
      f16x4 b = *(const f16x4*)&B[sg * ldB + d];
      f16x4 cm = *(const f16x4*)&Cm[sg * ldC + d];
      const float rinv = 1.0f / (float)(c * SC + s + 1);
      float m[4];
#pragma unroll
      for (int j = 0; j < 4; j++) {
        acc[j] += (float)b[j];
        m[j] = w[j] * acc[j] * rinv * (float)cm[j];
        ms[j] += m[j];
      }
      if (HALF_OUT) {
        f16x4 o;
#pragma unroll
        for (int j = 0; j < 4; j++) o[j] = (half_t)m[j];
        *(f16x4*)&OH[sg * D_MODEL + d] = o;
      } else {
        *(f32x4*)&OF[sg * D_MODEL + d] = *(f32x4*)m;
      }
    }
  } else {
#pragma unroll 4
    for (int s = 0; s < SC; s++) {
      const size_t sg = s0 + s;
      f16x4 a = *(const f16x4*)&A[sg * ldA + d];
      f16x4 b = *(const f16x4*)&B[sg * ldB + d];
      f16x4 cm = *(const f16x4*)&Cm[sg * ldC + d];
      const float rinv = 1.0f / (float)(c * SC + s + 1);
      float m[4];
#pragma unroll
      for (int j = 0; j < 4; j++) {
        acc[j] += (float)a[j] * (float)b[j];
        m[j] = acc[j] * rinv * (float)cm[j];
        ms[j] += m[j];
      }
      if (HALF_OUT) {
        f16x4 o;
#pragma unroll
        for (int j = 0; j < 4; j++) o[j] = (half_t)m[j];
        *(f16x4*)&OH[sg * D_MODEL + d] = o;
      } else {
        *(f32x4*)&OF[sg * D_MODEL + d] = *(f32x4*)m;
      }
    }
  }
  if (msum) *(f32x4*)&msum[idx] = *(f32x4*)ms;
}

extern "C" void kernel_launch(void* const* d_in, const int* in_sizes, int n_in,
                              void* d_out, int out_size, void* d_ws, size_t ws_size,
                              hipStream_t stream) {
  const float* x     = (const float*)d_in[0];
  const float* Wq    = (const float*)d_in[2];
  const float* bq    = (const float*)d_in[3];
  const float* Wqa   = (const float*)d_in[4];
  const float* bqa   = (const float*)d_in[5];
  const float* Wk    = (const float*)d_in[6];
  const float* bk    = (const float*)d_in[7];
  const float* Wka   = (const float*)d_in[8];
  const float* bka   = (const float*)d_in[9];
  const float* Wv    = (const float*)d_in[10];
  const float* bv    = (const float*)d_in[11];
  const float* gamma = (const float*)d_in[12];
  const float* beta  = (const float*)d_in[13];
  float* out = (float*)d_out;

  char* ws = (char*)d_ws;
  const size_t MB = 1024 * 1024;
  half_t* h16    = (half_t*)(ws + 0);         // 32MB: h, reused as mixed16
  half_t* qkv16  = (half_t*)(ws + 32 * MB);   // 96MB: [16384][3072] q|k|v
  half_t* logits = (half_t*)(ws + 128 * MB);  // 32MB (nz path only)
  half_t* wcat   = (half_t*)(ws + 160 * MB);  // 6MB (dead after gemm1)
  half_t* wqa16  = (half_t*)(ws + 166 * MB);  // 2MB
  half_t* wka16  = (half_t*)(ws + 168 * MB);  // 2MB
  float*  bcat   = (float*)(ws + 170 * MB);   // 12KB
  // fast-path chunk sums live in the logits region (unused when flags==0);
  // nz-path part + msum live in dead-wcat (written only after gemm1).
  float*  pz1    = (float*)(ws + 128 * MB);          // 2MB (gemm1-emitted sums of q)
  float*  pn     = (float*)(ws + 160 * MB);          // 2MB (nz path partials)
  float*  msum   = (float*)(ws + 162 * MB);          // 2MB (chunk sums of mixed)
  float*  qwv    = (float*)(ws + 170 * MB + 64 * 1024);  // 4KB
  float*  kwv    = (float*)(ws + 170 * MB + 68 * 1024);  // 4KB
  int*    flags  = (int*)(ws + 170 * MB + 72 * 1024);    // 8B
  unsigned* nzp  = (unsigned*)(ws + 170 * MB + 76 * 1024); // 2KB

  half_t* q16 = qkv16;            // ld 3072
  half_t* k16 = qkv16 + 1024;
  half_t* v16 = qkv16 + 2048;
  half_t* mixed16 = h16;
  half_t* sw = logits;

  hipFuncSetAttribute((const void*)gemm8, hipFuncAttributeMaxDynamicSharedMemorySize, 131072);

  setup1<<<22028, 256, 0, stream>>>(x, gamma, beta, h16, Wq, Wk, Wv, Wqa, Wka,
                                    wcat, wqa16, wka16, bq, bk, bv, bcat, nzp);
  setup2<<<2, 256, 0, stream>>>(nzp, flags, bqa, bka, qwv, kwv);
  // q|k|v = h @ [Wq|Wk|Wv] + b ; also emits chunk sums of q into pz1
  gemm8<<<dim3(12, 64), 512, 131072, stream>>>(h16, 1024, wcat, bcat, qkv16, 3072,
                                               nullptr, pz1);
  // logits = q @ Wqa + bqa  (skipped when Wqa == 0)
  gemm8<<<dim3(4, 64), 512, 131072, stream>>>(q16, 3072, wqa16, bqa, logits, 1024,
                                              flags, nullptr);
  softmax_k<<<2048, 256, 0, stream>>>(logits, sw, flags);
  // mixed = (cumsum(qw.*q)/scale) .* k
  cs_partial<<<dim3(1, NC, BS), 256, 0, stream>>>(flags, sw, 1024, q16, 3072, pn);
  cs_scan<<<dim3(4, BS), 256, 0, stream>>>(flags, pz1, pn);
  cs_apply<true><<<dim3(1, NC, BS), 256, 0, stream>>>(flags, qwv, sw, 1024, q16, 3072,
                                                      k16, 3072, pz1, pn, msum,
                                                      mixed16, nullptr);
  // logits = mixed @ Wka + bka  (skipped when Wka == 0)
  gemm8<<<dim3(4, 64), 512, 131072, stream>>>(mixed16, 1024, wka16, bka, logits, 1024,
                                              flags + 1, nullptr);
  softmax_k<<<2048, 256, 0, stream>>>(logits, sw, flags + 1);
  // out = (cumsum(kw.*mixed)/scale) .* v
  cs_partial<<<dim3(1, NC, BS), 256, 0, stream>>>(flags + 1, sw, 1024, mixed16, 1024, pn);
  cs_scan<<<dim3(4, BS), 256, 0, stream>>>(flags + 1, msum, pn);
  cs_apply<false><<<dim3(1, NC, BS), 256, 0, stream>>>(flags + 1, kwv, sw, 1024,
                                                       mixed16, 1024, v16, 3072,
                                                       msum, pn, nullptr, nullptr, out);
}

// Round 10
// 192.725 us; speedup vs baseline: 1.4853x; 1.0360x over previous
//
#include <hip/hip_runtime.h>

typedef _Float16 half_t;
typedef _Float16 f16x8 __attribute__((ext_vector_type(8)));
typedef _Float16 f16x4 __attribute__((ext_vector_type(4)));
typedef float f32x4 __attribute__((ext_vector_type(4)));

#define D_MODEL 1024
#define BS 4
#define SEQ 4096
#define ROWS (BS * SEQ)   // 16384
#define SC 32
#define NC (SEQ / SC)     // 128

#define BARRIER() asm volatile("s_barrier" ::: "memory")
#define WAITV(n)  asm volatile("s_waitcnt vmcnt(" #n ")" ::: "memory")

__device__ __forceinline__ void gld_lds16(const half_t* g, char* l) {
  __builtin_amdgcn_global_load_lds((const __attribute__((address_space(1))) void*)g,
                                   (__attribute__((address_space(3))) void*)l, 16, 0, 0);
}

// ================= setup1: ln + prep_w + detect_nz + copy_bias (fused) =================
__global__ __launch_bounds__(256) void setup1(const float* __restrict__ x,
                                              const float* __restrict__ gamma,
                                              const float* __restrict__ beta,
                                              half_t* __restrict__ h,
                                              const float* __restrict__ Wq,
                                              const float* __restrict__ Wk,
                                              const float* __restrict__ Wv,
                                              const float* __restrict__ Wqa,
                                              const float* __restrict__ Wka,
                                              half_t* __restrict__ wcat,
                                              half_t* __restrict__ wqa,
                                              half_t* __restrict__ wka,
                                              const float* __restrict__ bq,
                                              const float* __restrict__ bk,
                                              const float* __restrict__ bv,
                                              float* __restrict__ bcat,
                                              unsigned* __restrict__ nzpart) {
  __shared__ float sh[33 * 32];
  const int b = blockIdx.x;
  const int t = threadIdx.x;
  if (b < 16384) {
    // ---- layernorm row b ----
    const float* xr = x + (size_t)b * D_MODEL + t * 4;
    f32x4 v = *(const f32x4*)xr;
    float s = v[0] + v[1] + v[2] + v[3];
    float q = v[0]*v[0] + v[1]*v[1] + v[2]*v[2] + v[3]*v[3];
#pragma unroll
    for (int off = 32; off > 0; off >>= 1) {
      s += __shfl_down(s, off, 64);
      q += __shfl_down(q, off, 64);
    }
    const int wv = t >> 6, ln = t & 63;
    if (ln == 0) { sh[wv] = s; sh[4 + wv] = q; }
    __syncthreads();
    s = sh[0] + sh[1] + sh[2] + sh[3];
    q = sh[4] + sh[5] + sh[6] + sh[7];
    const float mu = s * (1.0f / D_MODEL);
    const float var = q * (1.0f / D_MODEL) - mu * mu;
    const float rstd = rsqrtf(var + 1e-5f);
    f32x4 g = *(const f32x4*)(gamma + t * 4);
    f32x4 bb = *(const f32x4*)(beta + t * 4);
    f16x4 o;
#pragma unroll
    for (int i = 0; i < 4; i++) o[i] = (half_t)((v[i] - mu) * rstd * g[i] + bb[i]);
    *(f16x4*)(h + (size_t)b * D_MODEL + t * 4) = o;
  } else if (b < 21504) {
    // ---- weight prepack tile ----
    const int bi = b - 16384;
    const int mat = bi >> 10;
    const int tile = bi & 1023;
    const int tn = (tile & 31) * 32;
    const int tk = (tile >> 5) * 32;
    const float* W = mat == 0 ? Wq : mat == 1 ? Wk : mat == 2 ? Wv : mat == 3 ? Wqa : Wka;
    half_t* dst = mat < 3 ? wcat + (size_t)mat * D_MODEL * D_MODEL : (mat == 3 ? wqa : wka);
    float (*tl)[33] = (float(*)[33])sh;
    const int tx = t & 31, ty = t >> 5;
#pragma unroll
    for (int i = 0; i < 32; i += 8)
      tl[ty + i][tx] = W[(size_t)(tk + ty + i) * D_MODEL + tn + tx];
    __syncthreads();
#pragma unroll
    for (int i = 0; i < 32; i += 8)
      dst[(size_t)(tn + ty + i) * D_MODEL + tk + tx] = (half_t)tl[tx][ty + i];
  } else if (b < 22016) {
    // ---- detect nonzero: per-block OR -> nzpart ----
    const int bi = b - 21504;
    const int which = bi >> 8;
    const unsigned* w = (const unsigned*)(which ? Wka : Wqa);
    const int blk = bi & 255;
    unsigned v = 0;
    const size_t base = (size_t)blk * 4096 + t;
#pragma unroll
    for (int i = 0; i < 16; ++i) v |= w[base + i * 256];
#pragma unroll
    for (int off = 32; off > 0; off >>= 1) v |= __shfl_down(v, off, 64);
    unsigned* sv = (unsigned*)sh;
    if ((t & 63) == 0) sv[t >> 6] = v;
    __syncthreads();
    if (t == 0) nzpart[bi] = sv[0] | sv[1] | sv[2] | sv[3];
  } else {
    // ---- copy_bias ----
    const int i = (b - 22016) * 256 + t;
    if (i < 1024) bcat[i] = bq[i];
    else if (i < 2048) bcat[i] = bk[i - 1024];
    else if (i < 3072) bcat[i] = bv[i - 2048];
  }
}

// ================= setup2: flag reduce + bias softmax (2 blocks) =================
__global__ __launch_bounds__(256) void setup2(const unsigned* __restrict__ nzpart,
                                              int* __restrict__ flags,
                                              const float* __restrict__ bqa,
                                              const float* __restrict__ bka,
                                              float* __restrict__ qwv,
                                              float* __restrict__ kwv) {
  const int b = blockIdx.x;
  const int t = threadIdx.x;
  __shared__ float sm[4], ssum[4];
  __shared__ unsigned su[4];
  unsigned u = nzpart[b * 256 + t];
#pragma unroll
  for (int off = 32; off > 0; off >>= 1) u |= __shfl_down(u, off, 64);
  const int wv = t >> 6, ln = t & 63;
  if (ln == 0) su[wv] = u;
  __syncthreads();
  if (t == 0) flags[b] = (su[0] | su[1] | su[2] | su[3]) ? 1 : 0;
  const float* bb = b ? bka : bqa;
  float* o = b ? kwv : qwv;
  f32x4 v = *(const f32x4*)(bb + t * 4);
  float xv[4];
#pragma unroll
  for (int i = 0; i < 4; i++) xv[i] = v[i] * 0.03125f;
  float mx = fmaxf(fmaxf(xv[0], xv[1]), fmaxf(xv[2], xv[3]));
#pragma unroll
  for (int off = 32; off > 0; off >>= 1) mx = fmaxf(mx, __shfl_xor(mx, off, 64));
  if (ln == 0) sm[wv] = mx;
  __syncthreads();
  mx = fmaxf(fmaxf(sm[0], sm[1]), fmaxf(sm[2], sm[3]));
  float e[4]; float s = 0.f;
#pragma unroll
  for (int i = 0; i < 4; i++) { e[i] = expf(xv[i] - mx); s += e[i]; }
#pragma unroll
  for (int off = 32; off > 0; off >>= 1) s += __shfl_xor(s, off, 64);
  if (ln == 0) ssum[wv] = s;
  __syncthreads();
  s = ssum[0] + ssum[1] + ssum[2] + ssum[3];
  const float r = 1.0f / s;
  f32x4 ov;
#pragma unroll
  for (int i = 0; i < 4; i++) ov[i] = e[i] * r;
  *(f32x4*)(o + t * 4) = ov;
}

// ================= 256x256 8-phase MFMA GEMM (16x16x32), K=1024 =================
// R5 schedule (frozen). If qp != null, blocks with n0 < 1024 also emit per-chunk
// (32-row) column sums of C (incl. bias) into qp[bb][chunk][col].

#define SA2(buf, rb, kt) do { \
  gld_lds16(gA + (size_t)((rb) + wbA + r8) * lda + (size_t)(kt) * 64 + grn * 8, \
            smem + (buf)*65536 + ((rb) + wbA) * 128); \
  gld_lds16(gA + (size_t)((rb) + 128 + wbA + r8) * lda + (size_t)(kt) * 64 + grn * 8, \
            smem + (buf)*65536 + ((rb) + 128 + wbA) * 128); \
} while (0)

#define SB2(buf, gd, kt) do { \
  gld_lds16(gB + (size_t)((gd) + wbB + r8) * 1024 + (size_t)(kt) * 64 + grn * 8, \
            smem + (buf)*65536 + 32768 + ((gd) + wbB) * 128); \
  gld_lds16(gB + (size_t)((gd) + 128 + wbB + r8) * 1024 + (size_t)(kt) * 64 + grn * 8, \
            smem + (buf)*65536 + 32768 + ((gd) + 128 + wbB) * 128); \
} while (0)

#define LOAD_A(buf, base) do { \
  _Pragma("unroll") for (int _fm = 0; _fm < 4; ++_fm) { \
    aF[_fm][0] = *(const f16x8*)(smem + (buf)*65536 + rA + gsw0 + ((base)+_fm)*2048); \
    aF[_fm][1] = *(const f16x8*)(smem + (buf)*65536 + rA + gsw1 + ((base)+_fm)*2048); \
  } \
} while (0)

#define LOAD_B(dst, buf, base) do { \
  _Pragma("unroll") for (int _fn = 0; _fn < 2; ++_fn) { \
    dst[_fn][0] = *(const f16x8*)(smem + (buf)*65536 + 32768 + rB + gsw0 + ((base)+_fn)*2048); \
    dst[_fn][1] = *(const f16x8*)(smem + (buf)*65536 + 32768 + rB + gsw1 + ((base)+_fn)*2048); \
  } \
} while (0)

#define QUAD(BR, MOFF, NOFF) do { \
  __builtin_amdgcn_s_setprio(1); \
  _Pragma("unroll") for (int _fm = 0; _fm < 4; ++_fm) \
  _Pragma("unroll") for (int _fn = 0; _fn < 2; ++_fn) { \
    acc[(MOFF)+_fm][(NOFF)+_fn] = __builtin_amdgcn_mfma_f32_16x16x32_f16(aF[_fm][0], BR[_fn][0], acc[(MOFF)+_fm][(NOFF)+_fn], 0, 0, 0); \
    acc[(MOFF)+_fm][(NOFF)+_fn] = __builtin_amdgcn_mfma_f32_16x16x32_f16(aF[_fm][1], BR[_fn][1], acc[(MOFF)+_fm][(NOFF)+_fn], 0, 0, 0); \
  } \
  __builtin_amdgcn_s_setprio(0); \
} while (0)

__global__ __launch_bounds__(512, 2) void gemm8(const half_t* __restrict__ A, int lda,
                                                const half_t* __restrict__ Bt,
                                                const float* __restrict__ bias,
                                                half_t* __restrict__ C, int ldc,
                                                const int* skip,
                                                float* __restrict__ qp) {
  if (skip && *skip == 0) return;
  extern __shared__ char smem[];
  const int t = threadIdx.x;
  const int ln = t & 63, wid = t >> 6;
  const int wm = wid >> 2, wn = wid & 3;

  const int gx = gridDim.x;
  const int nwg = gx * gridDim.y;
  const int orig = blockIdx.y * gx + blockIdx.x;
  const int swz = (orig & 7) * (nwg >> 3) + (orig >> 3);
  const int bx = swz % gx, by = swz / gx;
  const int n0 = bx * 256, m0 = by * 256;

  const int r8 = (t >> 3) & 7;
  const int grn = (t & 7) ^ r8;
  const int wbA = wid * 8;
  const int wbB = ((wid >> 2) << 6) + (wid & 3) * 8;
  const half_t* gA = A + (size_t)m0 * lda;
  const half_t* gB = Bt + (size_t)n0 * 1024;

  const int rA = (wm * 128 + (ln & 15)) * 128;
  const int rB = (wn * 64 + (ln & 15)) * 128;
  const int gsw0 = (((ln >> 4)) ^ (ln & 7)) << 4;
  const int gsw1 = ((4 | (ln >> 4)) ^ (ln & 7)) << 4;

  f32x4 acc[8][4] = {};
  f16x8 aF[4][2], bL[2][2], bH[2][2];

  SA2(0, 0, 0); SB2(0, 0, 0); SA2(0, 64, 0); SB2(0, 32, 0);
  SA2(1, 0, 1); SB2(1, 0, 1); SA2(1, 64, 1);
  WAITV(6); BARRIER();

#pragma unroll 1
  for (int i = 0; i < 8; ++i) {
    const int kb = 2 * i + 1;
    const int kc = 2 * i + 2;
    const int kd = 2 * i + 3;
    const bool f = (i < 7);
    LOAD_A(0, 0); LOAD_B(bL, 0, 0); LOAD_B(bH, 0, 2);
    SB2(1, 32, kb);
    QUAD(bL, 0, 0); BARRIER();
    if (f) SA2(0, 0, kc);
    QUAD(bH, 0, 2); BARRIER();
    LOAD_A(0, 4);
    if (f) SB2(0, 0, kc);
    QUAD(bH, 4, 2); BARRIER();
    if (f) { SA2(0, 64, kc); WAITV(6); } else WAITV(0);
    QUAD(bL, 4, 0); BARRIER();
    LOAD_A(1, 0); LOAD_B(bL, 1, 0); LOAD_B(bH, 1, 2);
    if (f) SB2(0, 32, kc);
    QUAD(bL, 0, 0); BARRIER();
    if (f) SA2(1, 0, kd);
    QUAD(bH, 0, 2); BARRIER();
    LOAD_A(1, 4);
    if (f) SB2(1, 0, kd);
    QUAD(bH, 4, 2); BARRIER();
    if (f) { SA2(1, 64, kd); WAITV(6); }
    QUAD(bL, 4, 0); BARRIER();
  }

  const int r0 = m0 + wm * 128 + ((ln >> 4) << 2);
  const int c0 = n0 + wn * 64 + (ln & 15);
  float bv4[4];
#pragma unroll
  for (int fn = 0; fn < 4; ++fn) bv4[fn] = bias[c0 + fn * 16];
#pragma unroll
  for (int fm = 0; fm < 8; ++fm)
#pragma unroll
    for (int fn = 0; fn < 4; ++fn) {
      const int col = c0 + fn * 16;
      const int row = r0 + fm * 16;
#pragma unroll
      for (int r = 0; r < 4; ++r)
        C[(size_t)(row + r) * ldc + col] = (half_t)(acc[fm][fn][r] + bv4[fn]);
    }

  if (qp && n0 < 1024) {
    const int bb = m0 >> 12;
    const int cb = ((m0 & 4095) >> 5) + wm * 4;
#pragma unroll
    for (int fn = 0; fn < 4; ++fn) {
#pragma unroll
      for (int j = 0; j < 4; ++j) {
        float s8 = bv4[fn] * 8.0f;
#pragma unroll
        for (int r = 0; r < 4; ++r) s8 += acc[2 * j][fn][r] + acc[2 * j + 1][fn][r];
        s8 += __shfl_xor(s8, 16, 64);
        s8 += __shfl_xor(s8, 32, 64);
        if (ln < 16)
          qp[((size_t)bb * NC + cb + j) * D_MODEL + c0 + fn * 16] = s8;
      }
    }
  }
}

// ================= row softmax (64 rows/block, nz path only) =================
__global__ __launch_bounds__(256) void softmax_k(const half_t* __restrict__ L,
                                                 half_t* __restrict__ O,
                                                 const int* skip) {
  if (*skip == 0) return;
  const int t = threadIdx.x;
  const int wv = t >> 6, ln = t & 63;
  __shared__ float sm[4], ssum[4];
#pragma unroll 1
  for (int i = 0; i < 64; ++i) {
    const size_t row = (size_t)blockIdx.x * 64 + i;
    f16x4 v = *(const f16x4*)(L + row * D_MODEL + t * 4);
    float x[4];
#pragma unroll
    for (int k = 0; k < 4; k++) x[k] = (float)v[k] * 0.03125f;
    float mx = fmaxf(fmaxf(x[0], x[1]), fmaxf(x[2], x[3]));
#pragma unroll
    for (int off = 32; off > 0; off >>= 1) mx = fmaxf(mx, __shfl_xor(mx, off, 64));
    if (ln == 0) sm[wv] = mx;
    __syncthreads();
    mx = fmaxf(fmaxf(sm[0], sm[1]), fmaxf(sm[2], sm[3]));
    float e[4]; float s = 0.f;
#pragma unroll
    for (int k = 0; k < 4; k++) { e[k] = expf(x[k] - mx); s += e[k]; }
#pragma unroll
    for (int off = 32; off > 0; off >>= 1) s += __shfl_xor(s, off, 64);
    if (ln == 0) ssum[wv] = s;
    __syncthreads();
    s = ssum[0] + ssum[1] + ssum[2] + ssum[3];
    const float r = 1.0f / s;
    f16x4 o;
#pragma unroll
    for (int k = 0; k < 4; k++) o[k] = (half_t)(e[k] * r);
    *(f16x4*)(O + row * D_MODEL + t * 4) = o;
    __syncthreads();
  }
}

// ================= cs_scan: (nz: compute partials) + exclusive chunk scan =================
// fast path: scans pz in place (gemm1- or cs_apply1-emitted chunk sums).
// nz path: computes partials of A.*B per chunk inline (scalar, untimed) into pn + scans.
__global__ __launch_bounds__(256) void cs_scan(const int* __restrict__ nz,
                                               float* __restrict__ pz,
                                               float* __restrict__ pn,
                                               const half_t* __restrict__ A, int ldA,
                                               const half_t* __restrict__ B, int ldB) {
  const int d = blockIdx.x * 256 + threadIdx.x;
  const int bb = blockIdx.y;
  if (*nz == 0) {
    float* p = pz + (size_t)bb * NC * D_MODEL + d;
    float acc = 0.f;
#pragma unroll 16
    for (int c = 0; c < NC; c++) {
      const float v = p[(size_t)c * D_MODEL];
      p[(size_t)c * D_MODEL] = acc;
      acc += v;
    }
  } else {
    float* p = pn + (size_t)bb * NC * D_MODEL + d;
    float acc = 0.f;
    for (int c = 0; c < NC; c++) {
      const size_t s0 = (size_t)bb * SEQ + (size_t)c * SC;
      float part = 0.f;
      for (int s = 0; s < SC; s++)
        part += (float)A[(s0 + s) * (size_t)ldA + d] * (float)B[(s0 + s) * (size_t)ldB + d];
      p[(size_t)c * D_MODEL] = acc;
      acc += part;
    }
  }
}

// ================= cumsum apply =================
// zero path: acc = prefix(plain sums); m = w * acc * rinv * Cm
// nz path:   acc = prefix(weighted sums); acc += A*B; m = acc * rinv * Cm
template <bool HALF_OUT>
__global__ __launch_bounds__(256) void cs_apply(const int* __restrict__ nz,
                                                const float* __restrict__ wv,
                                                const half_t* __restrict__ A, int ldA,
                                                const half_t* __restrict__ B, int ldB,
                                                const half_t* __restrict__ Cm, int ldC,
                                                const float* __restrict__ pz,
                                                const float* __restrict__ pn,
                                                float* __restrict__ msum,
                                                half_t* __restrict__ OH,
                                                float* __restrict__ OF) {
  const int d = threadIdx.x * 4;
  const int c = blockIdx.y;
  const int bb = blockIdx.z;
  const size_t idx = ((size_t)bb * NC + c) * D_MODEL + d;
  const int nzv = *nz;
  f32x4 pr = *(const f32x4*)((nzv == 0 ? pz : pn) + idx);
  float acc[4] = {pr[0], pr[1], pr[2], pr[3]};
  const size_t s0 = (size_t)bb * SEQ + (size_t)c * SC;
  float ms[4] = {};
  if (nzv == 0) {
    f32x4 w = *(const f32x4*)&wv[d];
#pragma unroll 4
    for (int s = 0; s < SC; s++) {
      const size_t sg = s0 + s;
      f16x4 b = *(const f16x4*)&B[sg * ldB + d];
      f16x4 cm = *(const f16x4*)&Cm[sg * ldC + d];
      const float rinv = 1.0f / (float)(c * SC + s + 1);
      float m[4];
#pragma unroll
      for (int j = 0; j < 4; j++) {
        acc[j] += (float)b[j];
        m[j] = w[j] * acc[j] * rinv * (float)cm[j];
        ms[j] += m[j];
      }
      if (HALF_OUT) {
        f16x4 o;
#pragma unroll
        for (int j = 0; j < 4; j++) o[j] = (half_t)m[j];
        *(f16x4*)&OH[sg * D_MODEL + d] = o;
      } else {
        *(f32x4*)&OF[sg * D_MODEL + d] = *(f32x4*)m;
      }
    }
  } else {
#pragma unroll 4
    for (int s = 0; s < SC; s++) {
      const size_t sg = s0 + s;
      f16x4 a = *(const f16x4*)&A[sg * ldA + d];
      f16x4 b = *(const f16x4*)&B[sg * ldB + d];
      f16x4 cm = *(const f16x4*)&Cm[sg * ldC + d];
      const float rinv = 1.0f / (float)(c * SC + s + 1);
      float m[4];
#pragma unroll
      for (int j = 0; j < 4; j++) {
        acc[j] += (float)a[j] * (float)b[j];
        m[j] = acc[j] * rinv * (float)cm[j];
        ms[j] += m[j];
      }
      if (HALF_OUT) {
        f16x4 o;
#pragma unroll
        for (int j = 0; j < 4; j++) o[j] = (half_t)m[j];
        *(f16x4*)&OH[sg * D_MODEL + d] = o;
      } else {
        *(f32x4*)&OF[sg * D_MODEL + d] = *(f32x4*)m;
      }
    }
  }
  if (msum) *(f32x4*)&msum[idx] = *(f32x4*)ms;
}

extern "C" void kernel_launch(void* const* d_in, const int* in_sizes, int n_in,
                              void* d_out, int out_size, void* d_ws, size_t ws_size,
                              hipStream_t stream) {
  const float* x     = (const float*)d_in[0];
  const float* Wq    = (const float*)d_in[2];
  const float* bq    = (const float*)d_in[3];
  const float* Wqa   = (const float*)d_in[4];
  const float* bqa   = (const float*)d_in[5];
  const float* Wk    = (const float*)d_in[6];
  const float* bk    = (const float*)d_in[7];
  const float* Wka   = (const float*)d_in[8];
  const float* bka   = (const float*)d_in[9];
  const float* Wv    = (const float*)d_in[10];
  const float* bv    = (const float*)d_in[11];
  const float* gamma = (const float*)d_in[12];
  const float* beta  = (const float*)d_in[13];
  float* out = (float*)d_out;

  char* ws = (char*)d_ws;
  const size_t MB = 1024 * 1024;
  half_t* h16    = (half_t*)(ws + 0);         // 32MB: h, reused as mixed16
  half_t* qkv16  = (half_t*)(ws + 32 * MB);   // 96MB: [16384][3072] q|k|v
  half_t* logits = (half_t*)(ws + 128 * MB);  // 32MB (nz path only)
  half_t* wcat   = (half_t*)(ws + 160 * MB);  // 6MB (dead after gemm1)
  half_t* wqa16  = (half_t*)(ws + 166 * MB);  // 2MB
  half_t* wka16  = (half_t*)(ws + 168 * MB);  // 2MB
  float*  bcat   = (float*)(ws + 170 * MB);   // 12KB
  float*  pz1    = (float*)(ws + 128 * MB);          // 2MB (gemm1-emitted sums of q)
  float*  pn     = (float*)(ws + 160 * MB);          // 2MB (nz path partials)
  float*  msum   = (float*)(ws + 162 * MB);          // 2MB (chunk sums of mixed)
  float*  qwv    = (float*)(ws + 170 * MB + 64 * 1024);  // 4KB
  float*  kwv    = (float*)(ws + 170 * MB + 68 * 1024);  // 4KB
  int*    flags  = (int*)(ws + 170 * MB + 72 * 1024);    // 8B
  unsigned* nzp  = (unsigned*)(ws + 170 * MB + 76 * 1024); // 2KB

  half_t* q16 = qkv16;            // ld 3072
  half_t* k16 = qkv16 + 1024;
  half_t* v16 = qkv16 + 2048;
  half_t* mixed16 = h16;
  half_t* sw = logits;

  hipFuncSetAttribute((const void*)gemm8, hipFuncAttributeMaxDynamicSharedMemorySize, 131072);

  setup1<<<22028, 256, 0, stream>>>(x, gamma, beta, h16, Wq, Wk, Wv, Wqa, Wka,
                                    wcat, wqa16, wka16, bq, bk, bv, bcat, nzp);
  setup2<<<2, 256, 0, stream>>>(nzp, flags, bqa, bka, qwv, kwv);
  // q|k|v = h @ [Wq|Wk|Wv] + b ; also emits chunk sums of q into pz1
  gemm8<<<dim3(12, 64), 512, 131072, stream>>>(h16, 1024, wcat, bcat, qkv16, 3072,
                                               nullptr, pz1);
  // logits = q @ Wqa + bqa  (skipped when Wqa == 0)
  gemm8<<<dim3(4, 64), 512, 131072, stream>>>(q16, 3072, wqa16, bqa, logits, 1024,
                                              flags, nullptr);
  softmax_k<<<256, 256, 0, stream>>>(logits, sw, flags);
  // scan stage 1: fast = scan pz1; nz = compute partials of sw.*q then scan
  cs_scan<<<dim3(4, BS), 256, 0, stream>>>(flags, pz1, pn, sw, 1024, q16, 3072);
  // mixed = (cumsum(qw.*q)/scale) .* k ; emits chunk sums of mixed into msum
  cs_apply<true><<<dim3(1, NC, BS), 256, 0, stream>>>(flags, qwv, sw, 1024, q16, 3072,
                                                      k16, 3072, pz1, pn, msum,
                                                      mixed16, nullptr);
  // logits = mixed @ Wka + bka  (skipped when Wka == 0)
  gemm8<<<dim3(4, 64), 512, 131072, stream>>>(mixed16, 1024, wka16, bka, logits, 1024,
                                              flags + 1, nullptr);
  softmax_k<<<256, 256, 0, stream>>>(logits, sw, flags + 1);
  // scan stage 2: fast = scan msum; nz = partials of sw.*mixed then scan
  cs_scan<<<dim3(4, BS), 256, 0, stream>>>(flags + 1, msum, pn, sw, 1024, mixed16, 1024);
  // out = (cumsum(kw.*mixed)/scale) .* v
  cs_apply<false><<<dim3(1, NC, BS), 256, 0, stream>>>(flags + 1, kwv, sw, 1024,
                                                       mixed16, 1024, v16, 3072,
                                                       msum, pn, nullptr, nullptr, out);
}

// Round 12
// 190.848 us; speedup vs baseline: 1.4999x; 1.0098x over previous
//
#include <hip/hip_runtime.h>

typedef _Float16 half_t;
typedef _Float16 f16x8 __attribute__((ext_vector_type(8)));
typedef _Float16 f16x4 __attribute__((ext_vector_type(4)));
typedef float f32x4 __attribute__((ext_vector_type(4)));

#define D_MODEL 1024
#define BS 4
#define SEQ 4096
#define ROWS (BS * SEQ)   // 16384
#define SC 32
#define NC (SEQ / SC)     // 128

#define BARRIER() asm volatile("s_barrier" ::: "memory")
#define WAITV(n)  asm volatile("s_waitcnt vmcnt(" #n ")" ::: "memory")

__device__ __forceinline__ void gld_lds16(const half_t* g, char* l) {
  __builtin_amdgcn_global_load_lds((const __attribute__((address_space(1))) void*)g,
                                   (__attribute__((address_space(3))) void*)l, 16, 0, 0);
}

// ================= setup1: ln + prep_w + detect_nz + copy_bias (fused) =================
__global__ __launch_bounds__(256) void setup1(const float* __restrict__ x,
                                              const float* __restrict__ gamma,
                                              const float* __restrict__ beta,
                                              half_t* __restrict__ h,
                                              const float* __restrict__ Wq,
                                              const float* __restrict__ Wk,
                                              const float* __restrict__ Wv,
                                              const float* __restrict__ Wqa,
                                              const float* __restrict__ Wka,
                                              half_t* __restrict__ wcat,
                                              half_t* __restrict__ wqa,
                                              half_t* __restrict__ wka,
                                              const float* __restrict__ bq,
                                              const float* __restrict__ bk,
                                              const float* __restrict__ bv,
                                              float* __restrict__ bcat,
                                              unsigned* __restrict__ nzpart) {
  __shared__ float sh[33 * 32];
  const int b = blockIdx.x;
  const int t = threadIdx.x;
  if (b < 16384) {
    // ---- layernorm row b (x is single-read: non-temporal) ----
    const float* xr = x + (size_t)b * D_MODEL + t * 4;
    f32x4 v = __builtin_nontemporal_load((const f32x4*)xr);
    float s = v[0] + v[1] + v[2] + v[3];
    float q = v[0]*v[0] + v[1]*v[1] + v[2]*v[2] + v[3]*v[3];
#pragma unroll
    for (int off = 32; off > 0; off >>= 1) {
      s += __shfl_down(s, off, 64);
      q += __shfl_down(q, off, 64);
    }
    const int wv = t >> 6, ln = t & 63;
    if (ln == 0) { sh[wv] = s; sh[4 + wv] = q; }
    __syncthreads();
    s = sh[0] + sh[1] + sh[2] + sh[3];
    q = sh[4] + sh[5] + sh[6] + sh[7];
    const float mu = s * (1.0f / D_MODEL);
    const float var = q * (1.0f / D_MODEL) - mu * mu;
    const float rstd = rsqrtf(var + 1e-5f);
    f32x4 g = *(const f32x4*)(gamma + t * 4);
    f32x4 bb = *(const f32x4*)(beta + t * 4);
    f16x4 o;
#pragma unroll
    for (int i = 0; i < 4; i++) o[i] = (half_t)((v[i] - mu) * rstd * g[i] + bb[i]);
    *(f16x4*)(h + (size_t)b * D_MODEL + t * 4) = o;
  } else if (b < 21504) {
    const int bi = b - 16384;
    const int mat = bi >> 10;
    const int tile = bi & 1023;
    const int tn = (tile & 31) * 32;
    const int tk = (tile >> 5) * 32;
    const float* W = mat == 0 ? Wq : mat == 1 ? Wk : mat == 2 ? Wv : mat == 3 ? Wqa : Wka;
    half_t* dst = mat < 3 ? wcat + (size_t)mat * D_MODEL * D_MODEL : (mat == 3 ? wqa : wka);
    float (*tl)[33] = (float(*)[33])sh;
    const int tx = t & 31, ty = t >> 5;
#pragma unroll
    for (int i = 0; i < 32; i += 8)
      tl[ty + i][tx] = W[(size_t)(tk + ty + i) * D_MODEL + tn + tx];
    __syncthreads();
#pragma unroll
    for (int i = 0; i < 32; i += 8)
      dst[(size_t)(tn + ty + i) * D_MODEL + tk + tx] = (half_t)tl[tx][ty + i];
  } else if (b < 22016) {
    const int bi = b - 21504;
    const int which = bi >> 8;
    const unsigned* w = (const unsigned*)(which ? Wka : Wqa);
    const int blk = bi & 255;
    unsigned v = 0;
    const size_t base = (size_t)blk * 4096 + t;
#pragma unroll
    for (int i = 0; i < 16; ++i) v |= w[base + i * 256];
#pragma unroll
    for (int off = 32; off > 0; off >>= 1) v |= __shfl_down(v, off, 64);
    unsigned* sv = (unsigned*)sh;
    if ((t & 63) == 0) sv[t >> 6] = v;
    __syncthreads();
    if (t == 0) nzpart[bi] = sv[0] | sv[1] | sv[2] | sv[3];
  } else {
    const int i = (b - 22016) * 256 + t;
    if (i < 1024) bcat[i] = bq[i];
    else if (i < 2048) bcat[i] = bk[i - 1024];
    else if (i < 3072) bcat[i] = bv[i - 2048];
  }
}

// ================= setup2: flag reduce + bias softmax (2 blocks) =================
__global__ __launch_bounds__(256) void setup2(const unsigned* __restrict__ nzpart,
                                              int* __restrict__ flags,
                                              const float* __restrict__ bqa,
                                              const float* __restrict__ bka,
                                              float* __restrict__ qwv,
                                              float* __restrict__ kwv) {
  const int b = blockIdx.x;
  const int t = threadIdx.x;
  __shared__ float sm[4], ssum[4];
  __shared__ unsigned su[4];
  unsigned u = nzpart[b * 256 + t];
#pragma unroll
  for (int off = 32; off > 0; off >>= 1) u |= __shfl_down(u, off, 64);
  const int wv = t >> 6, ln = t & 63;
  if (ln == 0) su[wv] = u;
  __syncthreads();
  if (t == 0) flags[b] = (su[0] | su[1] | su[2] | su[3]) ? 1 : 0;
  const float* bb = b ? bka : bqa;
  float* o = b ? kwv : qwv;
  f32x4 v = *(const f32x4*)(bb + t * 4);
  float xv[4];
#pragma unroll
  for (int i = 0; i < 4; i++) xv[i] = v[i] * 0.03125f;
  float mx = fmaxf(fmaxf(xv[0], xv[1]), fmaxf(xv[2], xv[3]));
#pragma unroll
  for (int off = 32; off > 0; off >>= 1) mx = fmaxf(mx, __shfl_xor(mx, off, 64));
  if (ln == 0) sm[wv] = mx;
  __syncthreads();
  mx = fmaxf(fmaxf(sm[0], sm[1]), fmaxf(sm[2], sm[3]));
  float e[4]; float s = 0.f;
#pragma unroll
  for (int i = 0; i < 4; i++) { e[i] = expf(xv[i] - mx); s += e[i]; }
#pragma unroll
  for (int off = 32; off > 0; off >>= 1) s += __shfl_xor(s, off, 64);
  if (ln == 0) ssum[wv] = s;
  __syncthreads();
  s = ssum[0] + ssum[1] + ssum[2] + ssum[3];
  const float r = 1.0f / s;
  f32x4 ov;
#pragma unroll
  for (int i = 0; i < 4; i++) ov[i] = e[i] * r;
  *(f32x4*)(o + t * 4) = ov;
}

// ================= 256x256 8-phase MFMA GEMM (16x16x32), K=1024 (frozen) =================

#define SA2(buf, rb, kt) do { \
  gld_lds16(gA + (size_t)((rb) + wbA + r8) * lda + (size_t)(kt) * 64 + grn * 8, \
            smem + (buf)*65536 + ((rb) + wbA) * 128); \
  gld_lds16(gA + (size_t)((rb) + 128 + wbA + r8) * lda + (size_t)(kt) * 64 + grn * 8, \
            smem + (buf)*65536 + ((rb) + 128 + wbA) * 128); \
} while (0)

#define SB2(buf, gd, kt) do { \
  gld_lds16(gB + (size_t)((gd) + wbB + r8) * 1024 + (size_t)(kt) * 64 + grn * 8, \
            smem + (buf)*65536 + 32768 + ((gd) + wbB) * 128); \
  gld_lds16(gB + (size_t)((gd) + 128 + wbB + r8) * 1024 + (size_t)(kt) * 64 + grn * 8, \
            smem + (buf)*65536 + 32768 + ((gd) + 128 + wbB) * 128); \
} while (0)

#define LOAD_A(buf, base) do { \
  _Pragma("unroll") for (int _fm = 0; _fm < 4; ++_fm) { \
    aF[_fm][0] = *(const f16x8*)(smem + (buf)*65536 + rA + gsw0 + ((base)+_fm)*2048); \
    aF[_fm][1] = *(const f16x8*)(smem + (buf)*65536 + rA + gsw1 + ((base)+_fm)*2048); \
  } \
} while (0)

#define LOAD_B(dst, buf, base) do { \
  _Pragma("unroll") for (int _fn = 0; _fn < 2; ++_fn) { \
    dst[_fn][0] = *(const f16x8*)(smem + (buf)*65536 + 32768 + rB + gsw0 + ((base)+_fn)*2048); \
    dst[_fn][1] = *(const f16x8*)(smem + (buf)*65536 + 32768 + rB + gsw1 + ((base)+_fn)*2048); \
  } \
} while (0)

#define QUAD(BR, MOFF, NOFF) do { \
  __builtin_amdgcn_s_setprio(1); \
  _Pragma("unroll") for (int _fm = 0; _fm < 4; ++_fm) \
  _Pragma("unroll") for (int _fn = 0; _fn < 2; ++_fn) { \
    acc[(MOFF)+_fm][(NOFF)+_fn] = __builtin_amdgcn_mfma_f32_16x16x32_f16(aF[_fm][0], BR[_fn][0], acc[(MOFF)+_fm][(NOFF)+_fn], 0, 0, 0); \
    acc[(MOFF)+_fm][(NOFF)+_fn] = __builtin_amdgcn_mfma_f32_16x16x32_f16(aF[_fm][1], BR[_fn][1], acc[(MOFF)+_fm][(NOFF)+_fn], 0, 0, 0); \
  } \
  __builtin_amdgcn_s_setprio(0); \
} while (0)

__global__ __launch_bounds__(512, 2) void gemm8(const half_t* __restrict__ A, int lda,
                                                const half_t* __restrict__ Bt,
                                                const float* __restrict__ bias,
                                                half_t* __restrict__ C, int ldc,
                                                const int* skip,
                                                float* __restrict__ qp) {
  if (skip && *skip == 0) return;
  extern __shared__ char smem[];
  const int t = threadIdx.x;
  const int ln = t & 63, wid = t >> 6;
  const int wm = wid >> 2, wn = wid & 3;

  const int gx = gridDim.x;
  const int nwg = gx * gridDim.y;
  const int orig = blockIdx.y * gx + blockIdx.x;
  const int swz = (orig & 7) * (nwg >> 3) + (orig >> 3);
  const int bx = swz % gx, by = swz / gx;
  const int n0 = bx * 256, m0 = by * 256;

  const int r8 = (t >> 3) & 7;
  const int grn = (t & 7) ^ r8;
  const int wbA = wid * 8;
  const int wbB = ((wid >> 2) << 6) + (wid & 3) * 8;
  const half_t* gA = A + (size_t)m0 * lda;
  const half_t* gB = Bt + (size_t)n0 * 1024;

  const int rA = (wm * 128 + (ln & 15)) * 128;
  const int rB = (wn * 64 + (ln & 15)) * 128;
  const int gsw0 = (((ln >> 4)) ^ (ln & 7)) << 4;
  const int gsw1 = ((4 | (ln >> 4)) ^ (ln & 7)) << 4;

  f32x4 acc[8][4] = {};
  f16x8 aF[4][2], bL[2][2], bH[2][2];

  SA2(0, 0, 0); SB2(0, 0, 0); SA2(0, 64, 0); SB2(0, 32, 0);
  SA2(1, 0, 1); SB2(1, 0, 1); SA2(1, 64, 1);
  WAITV(6); BARRIER();

#pragma unroll 1
  for (int i = 0; i < 8; ++i) {
    const int kb = 2 * i + 1;
    const int kc = 2 * i + 2;
    const int kd = 2 * i + 3;
    const bool f = (i < 7);
    LOAD_A(0, 0); LOAD_B(bL, 0, 0); LOAD_B(bH, 0, 2);
    SB2(1, 32, kb);
    QUAD(bL, 0, 0); BARRIER();
    if (f) SA2(0, 0, kc);
    QUAD(bH, 0, 2); BARRIER();
    LOAD_A(0, 4);
    if (f) SB2(0, 0, kc);
    QUAD(bH, 4, 2); BARRIER();
    if (f) { SA2(0, 64, kc); WAITV(6); } else WAITV(0);
    QUAD(bL, 4, 0); BARRIER();
    LOAD_A(1, 0); LOAD_B(bL, 1, 0); LOAD_B(bH, 1, 2);
    if (f) SB2(0, 32, kc);
    QUAD(bL, 0, 0); BARRIER();
    if (f) SA2(1, 0, kd);
    QUAD(bH, 0, 2); BARRIER();
    LOAD_A(1, 4);
    if (f) SB2(1, 0, kd);
    QUAD(bH, 4, 2); BARRIER();
    if (f) { SA2(1, 64, kd); WAITV(6); }
    QUAD(bL, 4, 0); BARRIER();
  }

  const int r0 = m0 + wm * 128 + ((ln >> 4) << 2);
  const int c0 = n0 + wn * 64 + (ln & 15);
  float bv4[4];
#pragma unroll
  for (int fn = 0; fn < 4; ++fn) bv4[fn] = bias[c0 + fn * 16];
#pragma unroll
  for (int fm = 0; fm < 8; ++fm)
#pragma unroll
    for (int fn = 0; fn < 4; ++fn) {
      const int col = c0 + fn * 16;
      const int row = r0 + fm * 16;
#pragma unroll
      for (int r = 0; r < 4; ++r)
        C[(size_t)(row + r) * ldc + col] = (half_t)(acc[fm][fn][r] + bv4[fn]);
    }

  if (qp && n0 < 1024) {
    const int bb = m0 >> 12;
    const int cb = ((m0 & 4095) >> 5) + wm * 4;
#pragma unroll
    for (int fn = 0; fn < 4; ++fn) {
#pragma unroll
      for (int j = 0; j < 4; ++j) {
        float s8 = bv4[fn] * 8.0f;
#pragma unroll
        for (int r = 0; r < 4; ++r) s8 += acc[2 * j][fn][r] + acc[2 * j + 1][fn][r];
        s8 += __shfl_xor(s8, 16, 64);
        s8 += __shfl_xor(s8, 32, 64);
        if (ln < 16)
          qp[((size_t)bb * NC + cb + j) * D_MODEL + c0 + fn * 16] = s8;
      }
    }
  }
}

// ================= row softmax (64 rows/block, nz path only) =================
__global__ __launch_bounds__(256) void softmax_k(const half_t* __restrict__ L,
                                                 half_t* __restrict__ O,
                                                 const int* skip) {
  if (*skip == 0) return;
  const int t = threadIdx.x;
  const int wv = t >> 6, ln = t & 63;
  __shared__ float sm[4], ssum[4];
#pragma unroll 1
  for (int i = 0; i < 64; ++i) {
    const size_t row = (size_t)blockIdx.x * 64 + i;
    f16x4 v = *(const f16x4*)(L + row * D_MODEL + t * 4);
    float x[4];
#pragma unroll
    for (int k = 0; k < 4; k++) x[k] = (float)v[k] * 0.03125f;
    float mx = fmaxf(fmaxf(x[0], x[1]), fmaxf(x[2], x[3]));
#pragma unroll
    for (int off = 32; off > 0; off >>= 1) mx = fmaxf(mx, __shfl_xor(mx, off, 64));
    if (ln == 0) sm[wv] = mx;
    __syncthreads();
    mx = fmaxf(fmaxf(sm[0], sm[1]), fmaxf(sm[2], sm[3]));
    float e[4]; float s = 0.f;
#pragma unroll
    for (int k = 0; k < 4; k++) { e[k] = expf(x[k] - mx); s += e[k]; }
#pragma unroll
    for (int off = 32; off > 0; off >>= 1) s += __shfl_xor(s, off, 64);
    if (ln == 0) ssum[wv] = s;
    __syncthreads();
    s = ssum[0] + ssum[1] + ssum[2] + ssum[3];
    const float r = 1.0f / s;
    f16x4 o;
#pragma unroll
    for (int k = 0; k < 4; k++) o[k] = (half_t)(e[k] * r);
    *(f16x4*)(O + row * D_MODEL + t * 4) = o;
    __syncthreads();
  }
}

// ================= cs_scan: (nz: compute partials) + exclusive chunk scan =================
__global__ __launch_bounds__(256) void cs_scan(const int* __restrict__ nz,
                                               float* __restrict__ pz,
                                               float* __restrict__ pn,
                                               const half_t* __restrict__ A, int ldA,
                                               const half_t* __restrict__ B, int ldB) {
  const int d = blockIdx.x * 256 + threadIdx.x;
  const int bb = blockIdx.y;
  if (*nz == 0) {
    float* p = pz + (size_t)bb * NC * D_MODEL + d;
    float acc = 0.f;
#pragma unroll 16
    for (int c = 0; c < NC; c++) {
      const float v = p[(size_t)c * D_MODEL];
      p[(size_t)c * D_MODEL] = acc;
      acc += v;
    }
  } else {
    float* p = pn + (size_t)bb * NC * D_MODEL + d;
    float acc = 0.f;
    for (int c = 0; c < NC; c++) {
      const size_t s0 = (size_t)bb * SEQ + (size_t)c * SC;
      float part = 0.f;
      for (int s = 0; s < SC; s++)
        part += (float)A[(s0 + s) * (size_t)ldA + d] * (float)B[(s0 + s) * (size_t)ldB + d];
      p[(size_t)c * D_MODEL] = acc;
      acc += part;
    }
  }
}

// ================= cumsum apply =================
template <bool HALF_OUT>
__global__ __launch_bounds__(256) void cs_apply(const int* __restrict__ nz,
                                                const float* __restrict__ wv,
                                                const half_t* __restrict__ A, int ldA,
                                                const half_t* __restrict__ B, int ldB,
                                                const half_t* __restrict__ Cm, int ldC,
                                                const float* __restrict__ pz,
                                                const float* __restrict__ pn,
                                                float* __restrict__ msum,
                                                half_t* __restrict__ OH,
                                                float* __restrict__ OF) {
  const int d = threadIdx.x * 4;
  const int c = blockIdx.y;
  const int bb = blockIdx.z;
  const size_t idx = ((size_t)bb * NC + c) * D_MODEL + d;
  const int nzv = *nz;
  f32x4 pr = *(const f32x4*)((nzv == 0 ? pz : pn) + idx);
  float acc[4] = {pr[0], pr[1], pr[2], pr[3]};
  const size_t s0 = (size_t)bb * SEQ + (size_t)c * SC;
  float ms[4] = {};
  if (nzv == 0) {
    f32x4 w = *(const f32x4*)&wv[d];
#pragma unroll 4
    for (int s = 0; s < SC; s++) {
      const size_t sg = s0 + s;
      f16x4 b = *(const f16x4*)&B[sg * ldB + d];
      f16x4 cm;
      if (HALF_OUT) cm = *(const f16x4*)&Cm[sg * ldC + d];
      else          cm = __builtin_nontemporal_load((const f16x4*)&Cm[sg * ldC + d]);
      const float rinv = 1.0f / (float)(c * SC + s + 1);
      float m[4];
#pragma unroll
      for (int j = 0; j < 4; j++) {
        acc[j] += (float)b[j];
        m[j] = w[j] * acc[j] * rinv * (float)cm[j];
        ms[j] += m[j];
      }
      if (HALF_OUT) {
        f16x4 o;
#pragma unroll
        for (int j = 0; j < 4; j++) o[j] = (half_t)m[j];
        *(f16x4*)&OH[sg * D_MODEL + d] = o;
      } else {
        __builtin_nontemporal_store(*(f32x4*)m, (f32x4*)&OF[sg * D_MODEL + d]);
      }
    }
  } else {
#pragma unroll 4
    for (int s = 0; s < SC; s++) {
      const size_t sg = s0 + s;
      f16x4 a = *(const f16x4*)&A[sg * ldA + d];
      f16x4 b = *(const f16x4*)&B[sg * ldB + d];
      f16x4 cm = *(const f16x4*)&Cm[sg * ldC + d];
      const float rinv = 1.0f / (float)(c * SC + s + 1);
      float m[4];
#pragma unroll
      for (int j = 0; j < 4; j++) {
        acc[j] += (float)a[j] * (float)b[j];
        m[j] = acc[j] * rinv * (float)cm[j];
        ms[j] += m[j];
      }
      if (HALF_OUT) {
        f16x4 o;
#pragma unroll
        for (int j = 0; j < 4; j++) o[j] = (half_t)m[j];
        *(f16x4*)&OH[sg * D_MODEL + d] = o;
      } else {
        __builtin_nontemporal_store(*(f32x4*)m, (f32x4*)&OF[sg * D_MODEL + d]);
      }
    }
  }
  if (msum) *(f32x4*)&msum[idx] = *(f32x4*)ms;
}

extern "C" void kernel_launch(void* const* d_in, const int* in_sizes, int n_in,
                              void* d_out, int out_size, void* d_ws, size_t ws_size,
                              hipStream_t stream) {
  const float* x     = (const float*)d_in[0];
  const float* Wq    = (const float*)d_in[2];
  const float* bq    = (const float*)d_in[3];
  const float* Wqa   = (const float*)d_in[4];
  const float* bqa   = (const float*)d_in[5];
  const float* Wk    = (const float*)d_in[6];
  const float* bk    = (const float*)d_in[7];
  const float* Wka   = (const float*)d_in[8];
  const float* bka   = (const float*)d_in[9];
  const float* Wv    = (const float*)d_in[10];
  const float* bv    = (const float*)d_in[11];
  const float* gamma = (const float*)d_in[12];
  const float* beta  = (const float*)d_in[13];
  float* out = (float*)d_out;

  char* ws = (char*)d_ws;
  const size_t MB = 1024 * 1024;
  half_t* h16    = (half_t*)(ws + 0);         // 32MB: h, reused as mixed16
  half_t* qkv16  = (half_t*)(ws + 32 * MB);   // 96MB
  half_t* logits = (half_t*)(ws + 128 * MB);  // 32MB (nz path only)
  half_t* wcat   = (half_t*)(ws + 160 * MB);  // 6MB (dead after gemm1)
  half_t* wqa16  = (half_t*)(ws + 166 * MB);  // 2MB
  half_t* wka16  = (half_t*)(ws + 168 * MB);  // 2MB
  float*  bcat   = (float*)(ws + 170 * MB);   // 12KB
  float*  pz1    = (float*)(ws + 128 * MB);          // 2MB (gemm1 chunk sums of q)
  float*  pn     = (float*)(ws + 160 * MB);          // 2MB (nz partials)
  float*  msum   = (float*)(ws + 162 * MB);          // 2MB (chunk sums of mixed)
  float*  qwv    = (float*)(ws + 170 * MB + 64 * 1024);  // 4KB
  float*  kwv    = (float*)(ws + 170 * MB + 68 * 1024);  // 4KB
  int*    flags  = (int*)(ws + 170 * MB + 72 * 1024);    // 8B
  unsigned* nzp  = (unsigned*)(ws + 170 * MB + 76 * 1024); // 2KB

  half_t* q16 = qkv16;            // ld 3072
  half_t* k16 = qkv16 + 1024;
  half_t* v16 = qkv16 + 2048;
  half_t* mixed16 = h16;
  half_t* sw = logits;

  hipFuncSetAttribute((const void*)gemm8, hipFuncAttributeMaxDynamicSharedMemorySize, 131072);

  setup1<<<22028, 256, 0, stream>>>(x, gamma, beta, h16, Wq, Wk, Wv, Wqa, Wka,
                                    wcat, wqa16, wka16, bq, bk, bv, bcat, nzp);
  setup2<<<2, 256, 0, stream>>>(nzp, flags, bqa, bka, qwv, kwv);
  // q|k|v = h @ [Wq|Wk|Wv] + b ; also emits chunk sums of q into pz1
  gemm8<<<dim3(12, 64), 512, 131072, stream>>>(h16, 1024, wcat, bcat, qkv16, 3072,
                                               nullptr, pz1);
  // logits = q @ Wqa + bqa  (skipped when Wqa == 0)
  gemm8<<<dim3(4, 64), 512, 131072, stream>>>(q16, 3072, wqa16, bqa, logits, 1024,
                                              flags, nullptr);
  softmax_k<<<256, 256, 0, stream>>>(logits, sw, flags);
  // scan stage 1: fast = scan pz1; nz = compute partials of sw.*q then scan
  cs_scan<<<dim3(4, BS), 256, 0, stream>>>(flags, pz1, pn, sw, 1024, q16, 3072);
  // mixed = (cumsum(qw.*q)/scale) .* k ; emits chunk sums of mixed into msum
  cs_apply<true><<<dim3(1, NC, BS), 256, 0, stream>>>(flags, qwv, sw, 1024, q16, 3072,
                                                      k16, 3072, pz1, pn, msum,
                                                      mixed16, nullptr);
  // logits = mixed @ Wka + bka  (skipped when Wka == 0)
  gemm8<<<dim3(4, 64), 512, 131072, stream>>>(mixed16, 1024, wka16, bka, logits, 1024,
                                              flags + 1, nullptr);
  softmax_k<<<256, 256, 0, stream>>>(logits, sw, flags + 1);
  // scan stage 2: fast = scan msum; nz = partials of sw.*mixed then scan
  cs_scan<<<dim3(4, BS), 256, 0, stream>>>(flags + 1, msum, pn, sw, 1024, mixed16, 1024);
  // out = (cumsum(kw.*mixed)/scale) .* v
  cs_apply<false><<<dim3(1, NC, BS), 256, 0, stream>>>(flags + 1, kwv, sw, 1024,
                                                       mixed16, 1024, v16, 3072,
                                                       msum, pn, nullptr, nullptr, out);
}